// Round 4
// baseline (119.608 us; speedup 1.0000x reference)
//
#include <hip/hip_runtime.h>

// ---------------------------------------------------------------------------
// NATTEN cross attention, MI355X round 4.
// Shapes: q (1,256,96,96) k (1,256,48,48) v (1,128,48,48)
// kernel_size=7 dilation=2 N_HEADS=8 d_head=32, output (1,128,96,96) f32.
// Window identity: nearest-exact 2x upsample + dilation-2 NATTEN cancel:
//   key/value tap for query (x,y) = (clip(x/2-3,0,41)+th, clip(y/2-3,0,41)+tw).
// Round-4 change: attention de-LDS'd. k (2.3MB) and v (1.2MB) are L2-resident;
// staging them in 62KB of LDS capped occupancy at 2 blocks/CU and generated
// ~400KB/block of LDS reads. Now: q in registers, k/v read from L2, softmax
// via shfl + 1.8KB LDS exchange. Thread u: pair p=u&31=(qi,h), residue r=u>>5,
// taps t = r, r+8, ... (each t covered exactly once).
// ---------------------------------------------------------------------------

#define C_IN   256
#define C_V    128
#define HQ     96
#define WQ     96
#define HK     48
#define WK     48
#define NPOS_Q (HQ*WQ)    // 9216
#define NPOS_K (HK*WK)    // 2304
#define NH     8
#define DH     32
#define KS     7
#define K2     49

#define TQ  (NPOS_Q/64)   // 144 M-tiles for Q proj
#define TK  (NPOS_K/64)   // 36  M-tiles for K proj

// ---- fused dual projection GEMM -------------------------------------------
// out_t[pos][o] = b[o] + sum_c w[o][c] * x[c][pos]
// blockIdx.x < TQ -> Q tiles, else K tiles. 64x64 tile, KC=16, 4x4 acc.
__global__ __launch_bounds__(256) void proj_gemm(
    const float* __restrict__ xq, const float* __restrict__ xk,
    const float* __restrict__ wq, const float* __restrict__ wk,
    const float* __restrict__ bq, const float* __restrict__ bk,
    float* __restrict__ qt, float* __restrict__ kt) {
  __shared__ float xs[2][16][68];
  __shared__ float ws[2][16][68];

  const int mb = blockIdx.x;
  const float* x; const float* w; const float* bias; float* outp;
  int npos, m0;
  if (mb < TQ) { x = xq; w = wq; bias = bq; outp = qt; npos = NPOS_Q; m0 = mb * 64; }
  else         { x = xk; w = wk; bias = bk; outp = kt; npos = NPOS_K; m0 = (mb - TQ) * 64; }
  const int n0 = blockIdx.y * 64;

  const int t  = threadIdx.x;
  const int tm = t & 15;
  const int tn = t >> 4;

  const int lx_kk = t >> 4;
  const int lx_m4 = (t & 15) * 4;
  const int lw_o  = t >> 2;
  const int lw_c4 = (t & 3) * 4;

  float acc[4][4];
#pragma unroll
  for (int i = 0; i < 4; ++i)
#pragma unroll
    for (int j = 0; j < 4; ++j) acc[i][j] = 0.f;

  float4 xv = *(const float4*)&x[(size_t)lx_kk * npos + m0 + lx_m4];
  float4 wv = *(const float4*)&w[(size_t)(n0 + lw_o) * C_IN + lw_c4];

  int p = 0;
  for (int c0 = 0; c0 < C_IN; c0 += 16, p ^= 1) {
    *(float4*)&xs[p][lx_kk][lx_m4] = xv;
    ws[p][lw_c4 + 0][lw_o] = wv.x;
    ws[p][lw_c4 + 1][lw_o] = wv.y;
    ws[p][lw_c4 + 2][lw_o] = wv.z;
    ws[p][lw_c4 + 3][lw_o] = wv.w;
    if (c0 + 16 < C_IN) {
      xv = *(const float4*)&x[(size_t)(c0 + 16 + lx_kk) * npos + m0 + lx_m4];
      wv = *(const float4*)&w[(size_t)(n0 + lw_o) * C_IN + c0 + 16 + lw_c4];
    }
    __syncthreads();
#pragma unroll
    for (int kk = 0; kk < 16; ++kk) {
      float4 a4 = *(const float4*)&xs[p][kk][tm * 4];
      float4 b4 = *(const float4*)&ws[p][kk][tn * 4];
      const float av[4] = {a4.x, a4.y, a4.z, a4.w};
      const float bv[4] = {b4.x, b4.y, b4.z, b4.w};
#pragma unroll
      for (int i = 0; i < 4; ++i)
#pragma unroll
        for (int j = 0; j < 4; ++j) acc[i][j] += av[i] * bv[j];
    }
  }

  const float4 bias4 = *(const float4*)&bias[n0 + tn * 4];
#pragma unroll
  for (int i = 0; i < 4; ++i) {
    float4 vv;
    vv.x = acc[i][0] + bias4.x;
    vv.y = acc[i][1] + bias4.y;
    vv.z = acc[i][2] + bias4.z;
    vv.w = acc[i][3] + bias4.w;
    *(float4*)&outp[(size_t)(m0 + tm * 4 + i) * C_IN + n0 + tn * 4] = vv;
  }
}

// ---- v transpose: vt[pos][c] = v[c][pos] ----------------------------------
__global__ __launch_bounds__(256) void transpose_v(
    const float* __restrict__ v, float* __restrict__ vt) {
  __shared__ float tile[C_V * 65];
  const int p0 = blockIdx.x * 64;
  const int u  = threadIdx.x;
  for (int i = u; i < C_V * 64; i += 256) {
    int c = i >> 6, p = i & 63;
    tile[c * 65 + p] = v[c * NPOS_K + p0 + p];
  }
  __syncthreads();
  for (int i = u; i < C_V * 64; i += 256) {
    int p = i >> 7, c = i & 127;
    vt[(p0 + p) * C_V + c] = tile[c * 65 + p];
  }
}

// ---- fused neighborhood attention (register + L2 fed) ---------------------
// block = 256 threads = 2x2 query tile; window (sh..sh+6, sw..sw+6).
__global__ __launch_bounds__(256) void natten_attn(
    const float* __restrict__ qt, const float* __restrict__ kt,
    const float* __restrict__ vt, float* __restrict__ out) {
  __shared__ float pmax_s[4][32];
  __shared__ float psum_s[4][32];
  __shared__ float pm_s[4 * 52];

  const int u  = threadIdx.x;
  const int a  = blockIdx.x;               // 0..47
  const int b  = blockIdx.y;               // 0..47
  const int sh = min(max(a - 3, 0), HK - KS);
  const int sw = min(max(b - 3, 0), WK - KS);

  const int p  = u & 31;                   // (qi,h) pair
  const int qi = p >> 3;
  const int h  = p & 7;
  const int r  = u >> 5;                   // tap residue 0..7
  const int w  = u >> 6;                   // wave id

  // q slice for this (qi,h): 32 floats in registers
  const int qx = 2 * a + (qi >> 1), qy = 2 * b + (qi & 1);
  const float4* q4 = (const float4*)&qt[(size_t)(qx * WQ + qy) * C_IN + h * DH];
  float4 qv[8];
#pragma unroll
  for (int j = 0; j < 8; ++j) qv[j] = q4[j];

  // logits for taps t = r + 8i, k straight from L2
  const float scale = 0.17677669529663687f;  // 32^-0.5
  float sreg[7];
#pragma unroll
  for (int i = 0; i < 7; ++i) {
    const int t  = r + 8 * i;
    const int tc = min(t, K2 - 1);
    const int th = tc / KS, tw = tc - th * KS;
    const float4* k4 =
        (const float4*)&kt[(size_t)((sh + th) * WK + (sw + tw)) * C_IN + h * DH];
    float s = 0.f;
#pragma unroll
    for (int j = 0; j < 8; ++j) {
      float4 kv = k4[j];
      s += qv[j].x * kv.x + qv[j].y * kv.y + qv[j].z * kv.z + qv[j].w * kv.w;
    }
    sreg[i] = (t < K2) ? s * scale : -1e30f;
  }

  // row max over 49 taps: 7 local + xor32 + cross-wave via LDS
  float m = sreg[0];
#pragma unroll
  for (int i = 1; i < 7; ++i) m = fmaxf(m, sreg[i]);
  m = fmaxf(m, __shfl_xor(m, 32));
  if ((u & 32) == 0) pmax_s[w][p] = m;
  __syncthreads();
  m = fmaxf(fmaxf(pmax_s[0][p], pmax_s[1][p]),
            fmaxf(pmax_s[2][p], pmax_s[3][p]));

  // exp + row sum
  float e[7];
  float sl = 0.f;
#pragma unroll
  for (int i = 0; i < 7; ++i) { e[i] = __expf(sreg[i] - m); sl += e[i]; }
  sl += __shfl_xor(sl, 32);
  __syncthreads();   // pmax_s reads done before psum_s reuse timing; keep phases clean
  if ((u & 32) == 0) psum_s[w][p] = sl;
  __syncthreads();
  const float sum = psum_s[0][p] + psum_s[1][p] + psum_s[2][p] + psum_s[3][p];
  const float rinv = 1.f / (8.f * sum);

  // head-mean: reduce over h (p bits 0..2) via shfl, lane h==0 writes pm
#pragma unroll
  for (int i = 0; i < 7; ++i) {
    float pv = e[i] * rinv;
    pv += __shfl_xor(pv, 1);
    pv += __shfl_xor(pv, 2);
    pv += __shfl_xor(pv, 4);
    const int t = r + 8 * i;
    if (h == 0 && t < K2) pm_s[qi * 52 + t] = pv;
  }
  __syncthreads();

  // PV: thread = (qi2, float2 c-slot), v straight from L2, pm broadcast
  const int qi2 = u >> 6;
  const int c2  = u & 63;
  const int qx2 = 2 * a + (qi2 >> 1), qy2 = 2 * b + (qi2 & 1);
  const float2* v2 = (const float2*)vt;
  float accx = 0.f, accy = 0.f;
#pragma unroll 7
  for (int t = 0; t < K2; ++t) {
    const int th = t / KS, tw = t - th * KS;
    const int pos = (sh + th) * WK + (sw + tw);
    const float pm = pm_s[qi2 * 52 + t];
    const float2 vv = v2[(size_t)pos * 64 + c2];
    accx += pm * vv.x;
    accy += pm * vv.y;
  }
  const int posq = qx2 * WQ + qy2;
  out[(size_t)(2 * c2 + 0) * NPOS_Q + posq] = accx;
  out[(size_t)(2 * c2 + 1) * NPOS_Q + posq] = accy;
}

// ---------------------------------------------------------------------------
extern "C" void kernel_launch(void* const* d_in, const int* in_sizes, int n_in,
                              void* d_out, int out_size, void* d_ws, size_t ws_size,
                              hipStream_t stream) {
  const float* q   = (const float*)d_in[0];
  const float* k   = (const float*)d_in[1];
  const float* v   = (const float*)d_in[2];
  const float* w_q = (const float*)d_in[3];
  const float* b_q = (const float*)d_in[4];
  const float* w_k = (const float*)d_in[5];
  const float* b_k = (const float*)d_in[6];
  float* out = (float*)d_out;

  float* qt = (float*)d_ws;                  // [9216][256]
  float* kt = qt + (size_t)NPOS_Q * C_IN;    // [2304][256]
  float* vt = kt + (size_t)NPOS_K * C_IN;    // [2304][128]

  proj_gemm<<<dim3(TQ + TK, 4), 256, 0, stream>>>(q, k, w_q, w_k, b_q, b_k, qt, kt);
  transpose_v<<<NPOS_K / 64, 256, 0, stream>>>(v, vt);
  natten_attn<<<dim3(HQ / 2, WQ / 2), 256, 0, stream>>>(qt, kt, vt, out);
}

// Round 5
// 75.575 us; speedup vs baseline: 1.5826x; 1.5826x over previous
//
#include <hip/hip_runtime.h>

// ---------------------------------------------------------------------------
// NATTEN cross attention, MI355X round 5.
// Window identity: key/value tap for query (x,y) =
//   (clip(x/2-3,0,41)+th, clip(y/2-3,0,41)+tw) in the native 48x48 grid.
// v5: attn = LDS-staged k (quad-transposed [t][j][h], conflict-free both ways)
//     + q in registers + in-register softmax (round-4 machinery) + v staged
//     into dead k buffer. LDS 51.7KB -> 3 blocks/CU. Proj: 128x64 tile,
//     acc[4][8] -> fewer LDS reads per FMA.
// ---------------------------------------------------------------------------

#define C_IN   256
#define C_V    128
#define HQ     96
#define WQ     96
#define HK     48
#define WK     48
#define NPOS_Q (HQ*WQ)    // 9216
#define NPOS_K (HK*WK)    // 2304
#define NH     8
#define DH     32
#define KS     7
#define K2     49
#define KQA    65         // k-row pitch in quads (attn LDS), odd
#define KQV    33         // v-row pitch in quads (attn LDS), odd

#define TQ2 (NPOS_Q/128)  // 72 M-tiles (Q proj)
#define TK2 (NPOS_K/128)  // 18 M-tiles (K proj)

// ---- fused dual projection GEMM -------------------------------------------
// out_t[pos][o] = b[o] + sum_c w[o][c] * x[c][pos]
// 128x64 tile, KC=16, 256 threads, acc[4][8], double-buffered LDS.
__global__ __launch_bounds__(256) void proj_gemm(
    const float* __restrict__ xq, const float* __restrict__ xk,
    const float* __restrict__ wq, const float* __restrict__ wk,
    const float* __restrict__ bq, const float* __restrict__ bk,
    float* __restrict__ qt, float* __restrict__ kt) {
  __shared__ float xs[2][16][132];   // 16 k-rows x 128 pos (+4 pad)
  __shared__ float ws[2][16][68];    // 16 k-rows x 64 o   (+4 pad)

  const int mb = blockIdx.x;
  const float* x; const float* w; const float* bias; float* outp;
  int npos, m0;
  if (mb < TQ2) { x = xq; w = wq; bias = bq; outp = qt; npos = NPOS_Q; m0 = mb * 128; }
  else          { x = xk; w = wk; bias = bk; outp = kt; npos = NPOS_K; m0 = (mb - TQ2) * 128; }
  const int n0 = blockIdx.y * 64;

  const int t  = threadIdx.x;
  const int tm = t & 31;           // m-frag: rows tm*4..tm*4+3
  const int tn = t >> 5;           // n-frag: cols tn*8..tn*8+7

  // staging indices
  const int xr0 = t >> 5;          // x row for i=t       (0..7)
  const int xr1 = xr0 + 8;         // x row for i=t+256   (8..15)
  const int xcq = (t & 31) * 4;    // x col (floats)
  const int wo  = t >> 2;          // w: output row 0..63
  const int wc4 = (t & 3) * 4;     // w: c quad within chunk

  float acc[4][8];
#pragma unroll
  for (int i = 0; i < 4; ++i)
#pragma unroll
    for (int j = 0; j < 8; ++j) acc[i][j] = 0.f;

  float4 xv0 = *(const float4*)&x[(size_t)xr0 * npos + m0 + xcq];
  float4 xv1 = *(const float4*)&x[(size_t)xr1 * npos + m0 + xcq];
  float4 wv  = *(const float4*)&w[(size_t)(n0 + wo) * C_IN + wc4];

  int p = 0;
  for (int c0 = 0; c0 < C_IN; c0 += 16, p ^= 1) {
    *(float4*)&xs[p][xr0][xcq] = xv0;
    *(float4*)&xs[p][xr1][xcq] = xv1;
    ws[p][wc4 + 0][wo] = wv.x;
    ws[p][wc4 + 1][wo] = wv.y;
    ws[p][wc4 + 2][wo] = wv.z;
    ws[p][wc4 + 3][wo] = wv.w;
    if (c0 + 16 < C_IN) {
      xv0 = *(const float4*)&x[(size_t)(c0 + 16 + xr0) * npos + m0 + xcq];
      xv1 = *(const float4*)&x[(size_t)(c0 + 16 + xr1) * npos + m0 + xcq];
      wv  = *(const float4*)&w[(size_t)(n0 + wo) * C_IN + c0 + 16 + wc4];
    }
    __syncthreads();
#pragma unroll
    for (int kk = 0; kk < 16; ++kk) {
      float4 a4 = *(const float4*)&xs[p][kk][tm * 4];
      float4 b0 = *(const float4*)&ws[p][kk][tn * 8];
      float4 b1 = *(const float4*)&ws[p][kk][tn * 8 + 4];
      const float av[4] = {a4.x, a4.y, a4.z, a4.w};
      const float bv[8] = {b0.x, b0.y, b0.z, b0.w, b1.x, b1.y, b1.z, b1.w};
#pragma unroll
      for (int i = 0; i < 4; ++i)
#pragma unroll
        for (int j = 0; j < 8; ++j) acc[i][j] += av[i] * bv[j];
    }
  }

  const float4 ba = *(const float4*)&bias[n0 + tn * 8];
  const float4 bb = *(const float4*)&bias[n0 + tn * 8 + 4];
#pragma unroll
  for (int i = 0; i < 4; ++i) {
    float4 v0, v1;
    v0.x = acc[i][0] + ba.x;  v0.y = acc[i][1] + ba.y;
    v0.z = acc[i][2] + ba.z;  v0.w = acc[i][3] + ba.w;
    v1.x = acc[i][4] + bb.x;  v1.y = acc[i][5] + bb.y;
    v1.z = acc[i][6] + bb.z;  v1.w = acc[i][7] + bb.w;
    float* row = &outp[(size_t)(m0 + tm * 4 + i) * C_IN + n0 + tn * 8];
    *(float4*)row       = v0;
    *(float4*)(row + 4) = v1;
  }
}

// ---- v transpose: vt[pos][c] = v[c][pos] ----------------------------------
__global__ __launch_bounds__(256) void transpose_v(
    const float* __restrict__ v, float* __restrict__ vt) {
  __shared__ float tile[C_V * 65];
  const int p0 = blockIdx.x * 64;
  const int u  = threadIdx.x;
  for (int i = u; i < C_V * 64; i += 256) {
    int c = i >> 6, p = i & 63;
    tile[c * 65 + p] = v[c * NPOS_K + p0 + p];
  }
  __syncthreads();
  for (int i = u; i < C_V * 64; i += 256) {
    int p = i >> 7, c = i & 127;
    vt[(p0 + p) * C_V + c] = tile[c * 65 + p];
  }
}

// ---- fused neighborhood attention -----------------------------------------
// block = 256 threads = 2x2 query tile; window (sh..sh+6, sw..sw+6).
// Thread u: pair p=u&31 -> (qi,h); tap residue r=u>>5; q in registers;
// k in LDS quad-transposed [t][j][h]; v staged into same buffer for PV.
__global__ __launch_bounds__(256) void natten_attn(
    const float* __restrict__ qt, const float* __restrict__ kt,
    const float* __restrict__ vt, float* __restrict__ out) {
  __shared__ float kv_s[K2 * KQA * 4];     // 50.96 KB; v phase uses 49*33 quads
  __shared__ float pmax_s[4][32];
  __shared__ float psum_s[4][32];
  __shared__ float pm_s[4 * 52];

  const int u  = threadIdx.x;
  const int a  = blockIdx.x;               // 0..47
  const int b  = blockIdx.y;               // 0..47
  const int sh = min(max(a - 3, 0), HK - KS);
  const int sw = min(max(b - 3, 0), WK - KS);

  const int p  = u & 31;                   // (qi,h)
  const int qi = p >> 3;
  const int h  = p & 7;
  const int r  = u >> 5;                   // tap residue 0..7
  const int w  = u >> 6;                   // wave id

  float4* kv4 = (float4*)kv_s;

  // ---- stage k window: quad jj (=h*8+j) of row t -> kv4[t*65 + j*8 + h] ----
  for (int i = u; i < K2 * 64; i += 256) {
    int tp = i >> 6, jj = i & 63;
    int th = tp / KS, tw = tp - th * KS;
    kv4[tp * KQA + ((jj & 7) << 3) + (jj >> 3)] =
        *(const float4*)&kt[(size_t)((sh + th) * WK + (sw + tw)) * C_IN + jj * 4];
  }

  // q slice for this (qi,h): 32 floats in registers
  const int qx = 2 * a + (qi >> 1), qy = 2 * b + (qi & 1);
  const float4* q4 = (const float4*)&qt[(size_t)(qx * WQ + qy) * C_IN + h * DH];
  float4 qv[8];
#pragma unroll
  for (int j = 0; j < 8; ++j) qv[j] = q4[j];
  __syncthreads();

  // ---- logits: taps t = r + 8i, k from LDS --------------------------------
  const float scale = 0.17677669529663687f;  // 32^-0.5
  float sreg[7];
#pragma unroll
  for (int i = 0; i < 7; ++i) {
    const int t  = r + 8 * i;
    const int tc = min(t, K2 - 1);
    const float4* k4 = &kv4[tc * KQA + h];   // stride 8 quads over j
    float s = 0.f;
#pragma unroll
    for (int j = 0; j < 8; ++j) {
      float4 kv = k4[j * 8];
      s += qv[j].x * kv.x + qv[j].y * kv.y + qv[j].z * kv.z + qv[j].w * kv.w;
    }
    sreg[i] = (t < K2) ? s * scale : -1e30f;
  }

  // ---- softmax (in-register, cross-wave via tiny LDS) ---------------------
  float m = sreg[0];
#pragma unroll
  for (int i = 1; i < 7; ++i) m = fmaxf(m, sreg[i]);
  m = fmaxf(m, __shfl_xor(m, 32));
  if ((u & 32) == 0) pmax_s[w][p] = m;
  __syncthreads();                           // S1: k reads done, pmax ready
  m = fmaxf(fmaxf(pmax_s[0][p], pmax_s[1][p]),
            fmaxf(pmax_s[2][p], pmax_s[3][p]));

  float e[7];
  float sl = 0.f;
#pragma unroll
  for (int i = 0; i < 7; ++i) { e[i] = __expf(sreg[i] - m); sl += e[i]; }
  sl += __shfl_xor(sl, 32);
  if ((u & 32) == 0) psum_s[w][p] = sl;

  // ---- stage v into dead k buffer: row t -> kv4[t*33 + c4] ----------------
  for (int i = u; i < K2 * 32; i += 256) {
    int tp = i >> 5, c4 = i & 31;
    int th = tp / KS, tw = tp - th * KS;
    kv4[tp * KQV + c4] =
        *(const float4*)&vt[(size_t)((sh + th) * WK + (sw + tw)) * C_V + c4 * 4];
  }
  __syncthreads();                           // S2: psum + v ready

  const float sum = psum_s[0][p] + psum_s[1][p] + psum_s[2][p] + psum_s[3][p];
  const float rinv = 1.f / (8.f * sum);

  // head-mean over h via shfl; lane h==0 writes pm
#pragma unroll
  for (int i = 0; i < 7; ++i) {
    float pv = e[i] * rinv;
    pv += __shfl_xor(pv, 1);
    pv += __shfl_xor(pv, 2);
    pv += __shfl_xor(pv, 4);
    const int t = r + 8 * i;
    if (h == 0 && t < K2) pm_s[qi * 52 + t] = pv;
  }
  __syncthreads();                           // S3: pm ready

  // ---- PV: wave = query, lane = float2 channel slot, v from LDS -----------
  const int qi2 = w;
  const int l   = u & 63;
  const int qx2 = 2 * a + (qi2 >> 1), qy2 = 2 * b + (qi2 & 1);
  const float2* v2 = (const float2*)kv_s;    // row pitch 66 float2
  float ax = 0.f, ay = 0.f;
#pragma unroll 7
  for (int t = 0; t < K2; ++t) {
    const float pm = pm_s[qi2 * 52 + t];
    const float2 vv = v2[t * (KQV * 2) + l];
    ax += pm * vv.x;
    ay += pm * vv.y;
  }
  const int posq = qx2 * WQ + qy2;
  out[(size_t)(2 * l + 0) * NPOS_Q + posq] = ax;
  out[(size_t)(2 * l + 1) * NPOS_Q + posq] = ay;
}

// ---------------------------------------------------------------------------
extern "C" void kernel_launch(void* const* d_in, const int* in_sizes, int n_in,
                              void* d_out, int out_size, void* d_ws, size_t ws_size,
                              hipStream_t stream) {
  const float* q   = (const float*)d_in[0];
  const float* k   = (const float*)d_in[1];
  const float* v   = (const float*)d_in[2];
  const float* w_q = (const float*)d_in[3];
  const float* b_q = (const float*)d_in[4];
  const float* w_k = (const float*)d_in[5];
  const float* b_k = (const float*)d_in[6];
  float* out = (float*)d_out;

  float* qt = (float*)d_ws;                  // [9216][256]
  float* kt = qt + (size_t)NPOS_Q * C_IN;    // [2304][256]
  float* vt = kt + (size_t)NPOS_K * C_IN;    // [2304][128]

  proj_gemm<<<dim3(TQ2 + TK2, 4), 256, 0, stream>>>(q, k, w_q, w_k, b_q, b_k, qt, kt);
  transpose_v<<<NPOS_K / 64, 256, 0, stream>>>(v, vt);
  natten_attn<<<dim3(HQ / 2, WQ / 2), 256, 0, stream>>>(qt, kt, vt, out);
}

// Round 6
// 73.608 us; speedup vs baseline: 1.6249x; 1.0267x over previous
//
#include <hip/hip_runtime.h>

// ---------------------------------------------------------------------------
// NATTEN cross attention, MI355X round 6.
// Window identity: key/value tap for query (x,y) =
//   (clip(x/2-3,0,41)+th, clip(y/2-3,0,41)+tw) in the native 48x48 grid.
// v6: round-5 + k LDS layout changed from quad-TRANSPOSE (write-pathological:
//     8-way ds_write_b128 conflict = 56 extra cyc x 49 instrs x 2304 blocks
//     = the measured 6.32M SQ_LDS_BANK_CONFLICT) to quad XOR-SWIZZLE
//     [t][j*8 + (h^j)]: both staging writes (lanes vary j) and logits reads
//     (lanes vary h, fixed j) cover all 8 LDS 16B-granule classes.
// ---------------------------------------------------------------------------

#define C_IN   256
#define C_V    128
#define HQ     96
#define WQ     96
#define HK     48
#define WK     48
#define NPOS_Q (HQ*WQ)    // 9216
#define NPOS_K (HK*WK)    // 2304
#define NH     8
#define DH     32
#define KS     7
#define K2     49
#define KQA    65         // k-row pitch in quads (attn LDS), odd
#define KQV    33         // v-row pitch in quads (attn LDS), odd

#define TQ2 (NPOS_Q/128)  // 72 M-tiles (Q proj)
#define TK2 (NPOS_K/128)  // 18 M-tiles (K proj)

// ---- fused dual projection GEMM -------------------------------------------
// out_t[pos][o] = b[o] + sum_c w[o][c] * x[c][pos]
// 128x64 tile, KC=16, 256 threads, acc[4][8], double-buffered LDS.
__global__ __launch_bounds__(256) void proj_gemm(
    const float* __restrict__ xq, const float* __restrict__ xk,
    const float* __restrict__ wq, const float* __restrict__ wk,
    const float* __restrict__ bq, const float* __restrict__ bk,
    float* __restrict__ qt, float* __restrict__ kt) {
  __shared__ float xs[2][16][132];   // 16 k-rows x 128 pos (+4 pad)
  __shared__ float ws[2][16][68];    // 16 k-rows x 64 o   (+4 pad)

  const int mb = blockIdx.x;
  const float* x; const float* w; const float* bias; float* outp;
  int npos, m0;
  if (mb < TQ2) { x = xq; w = wq; bias = bq; outp = qt; npos = NPOS_Q; m0 = mb * 128; }
  else          { x = xk; w = wk; bias = bk; outp = kt; npos = NPOS_K; m0 = (mb - TQ2) * 128; }
  const int n0 = blockIdx.y * 64;

  const int t  = threadIdx.x;
  const int tm = t & 31;           // m-frag: rows tm*4..tm*4+3
  const int tn = t >> 5;           // n-frag: cols tn*8..tn*8+7

  const int xr0 = t >> 5;          // x row for i=t       (0..7)
  const int xr1 = xr0 + 8;         // x row for i=t+256   (8..15)
  const int xcq = (t & 31) * 4;    // x col (floats)
  const int wo  = t >> 2;          // w: output row 0..63
  const int wc4 = (t & 3) * 4;     // w: c quad within chunk

  float acc[4][8];
#pragma unroll
  for (int i = 0; i < 4; ++i)
#pragma unroll
    for (int j = 0; j < 8; ++j) acc[i][j] = 0.f;

  float4 xv0 = *(const float4*)&x[(size_t)xr0 * npos + m0 + xcq];
  float4 xv1 = *(const float4*)&x[(size_t)xr1 * npos + m0 + xcq];
  float4 wv  = *(const float4*)&w[(size_t)(n0 + wo) * C_IN + wc4];

  int p = 0;
  for (int c0 = 0; c0 < C_IN; c0 += 16, p ^= 1) {
    *(float4*)&xs[p][xr0][xcq] = xv0;
    *(float4*)&xs[p][xr1][xcq] = xv1;
    ws[p][wc4 + 0][wo] = wv.x;
    ws[p][wc4 + 1][wo] = wv.y;
    ws[p][wc4 + 2][wo] = wv.z;
    ws[p][wc4 + 3][wo] = wv.w;
    if (c0 + 16 < C_IN) {
      xv0 = *(const float4*)&x[(size_t)(c0 + 16 + xr0) * npos + m0 + xcq];
      xv1 = *(const float4*)&x[(size_t)(c0 + 16 + xr1) * npos + m0 + xcq];
      wv  = *(const float4*)&w[(size_t)(n0 + wo) * C_IN + c0 + 16 + wc4];
    }
    __syncthreads();
#pragma unroll
    for (int kk = 0; kk < 16; ++kk) {
      float4 a4 = *(const float4*)&xs[p][kk][tm * 4];
      float4 b0 = *(const float4*)&ws[p][kk][tn * 8];
      float4 b1 = *(const float4*)&ws[p][kk][tn * 8 + 4];
      const float av[4] = {a4.x, a4.y, a4.z, a4.w};
      const float bv[8] = {b0.x, b0.y, b0.z, b0.w, b1.x, b1.y, b1.z, b1.w};
#pragma unroll
      for (int i = 0; i < 4; ++i)
#pragma unroll
        for (int j = 0; j < 8; ++j) acc[i][j] += av[i] * bv[j];
    }
  }

  const float4 ba = *(const float4*)&bias[n0 + tn * 8];
  const float4 bb = *(const float4*)&bias[n0 + tn * 8 + 4];
#pragma unroll
  for (int i = 0; i < 4; ++i) {
    float4 v0, v1;
    v0.x = acc[i][0] + ba.x;  v0.y = acc[i][1] + ba.y;
    v0.z = acc[i][2] + ba.z;  v0.w = acc[i][3] + ba.w;
    v1.x = acc[i][4] + bb.x;  v1.y = acc[i][5] + bb.y;
    v1.z = acc[i][6] + bb.z;  v1.w = acc[i][7] + bb.w;
    float* row = &outp[(size_t)(m0 + tm * 4 + i) * C_IN + n0 + tn * 8];
    *(float4*)row       = v0;
    *(float4*)(row + 4) = v1;
  }
}

// ---- v transpose: vt[pos][c] = v[c][pos] ----------------------------------
__global__ __launch_bounds__(256) void transpose_v(
    const float* __restrict__ v, float* __restrict__ vt) {
  __shared__ float tile[C_V * 65];
  const int p0 = blockIdx.x * 64;
  const int u  = threadIdx.x;
  for (int i = u; i < C_V * 64; i += 256) {
    int c = i >> 6, p = i & 63;
    tile[c * 65 + p] = v[c * NPOS_K + p0 + p];
  }
  __syncthreads();
  for (int i = u; i < C_V * 64; i += 256) {
    int p = i >> 7, c = i & 127;
    vt[(p0 + p) * C_V + c] = tile[c * 65 + p];
  }
}

// ---- fused neighborhood attention -----------------------------------------
// block = 256 threads = 2x2 query tile; window (sh..sh+6, sw..sw+6).
// Thread u: pair p=u&31 -> (qi,h); tap residue r=u>>5; q in registers;
// k in LDS XOR-swizzled [t][j*8+(h^j)]; v staged into same buffer for PV.
__global__ __launch_bounds__(256) void natten_attn(
    const float* __restrict__ qt, const float* __restrict__ kt,
    const float* __restrict__ vt, float* __restrict__ out) {
  __shared__ float kv_s[K2 * KQA * 4];     // 50.96 KB; v phase uses 49*33 quads
  __shared__ float pmax_s[4][32];
  __shared__ float psum_s[4][32];
  __shared__ float pm_s[4 * 52];

  const int u  = threadIdx.x;
  const int a  = blockIdx.x;               // 0..47
  const int b  = blockIdx.y;               // 0..47
  const int sh = min(max(a - 3, 0), HK - KS);
  const int sw = min(max(b - 3, 0), WK - KS);

  const int p  = u & 31;                   // (qi,h)
  const int qi = p >> 3;
  const int h  = p & 7;
  const int r  = u >> 5;                   // tap residue 0..7
  const int w  = u >> 6;                   // wave id

  float4* kv4 = (float4*)kv_s;

  // ---- stage k window: input quad jj=(h',j) of row t -> kv4[t*65 + j*8 + (h'^j)]
  // write granule class = h'^j: each in-order 8-lane group covers all 8 classes.
  for (int i = u; i < K2 * 64; i += 256) {
    int tp = i >> 6, jj = i & 63;
    int th = tp / KS, tw = tp - th * KS;
    int hh = jj >> 3, j = jj & 7;
    kv4[tp * KQA + j * 8 + (hh ^ j)] =
        *(const float4*)&kt[(size_t)((sh + th) * WK + (sw + tw)) * C_IN + jj * 4];
  }

  // q slice for this (qi,h): 32 floats in registers
  const int qx = 2 * a + (qi >> 1), qy = 2 * b + (qi & 1);
  const float4* q4 = (const float4*)&qt[(size_t)(qx * WQ + qy) * C_IN + h * DH];
  float4 qv[8];
#pragma unroll
  for (int j = 0; j < 8; ++j) qv[j] = q4[j];
  __syncthreads();

  // ---- logits: taps t = r + 8i, k from LDS (fixed j: lanes vary h -> h^j
  // covers all 8 granule classes; 2 taps/wave differ by 65==1 mod 8) --------
  const float scale = 0.17677669529663687f;  // 32^-0.5
  float sreg[7];
#pragma unroll
  for (int i = 0; i < 7; ++i) {
    const int t  = r + 8 * i;
    const int tc = min(t, K2 - 1);
    const float4* krow = &kv4[tc * KQA];
    float s = 0.f;
#pragma unroll
    for (int j = 0; j < 8; ++j) {
      float4 kv = krow[j * 8 + (h ^ j)];
      s += qv[j].x * kv.x + qv[j].y * kv.y + qv[j].z * kv.z + qv[j].w * kv.w;
    }
    sreg[i] = (t < K2) ? s * scale : -1e30f;
  }

  // ---- softmax (in-register, cross-wave via tiny LDS) ---------------------
  float m = sreg[0];
#pragma unroll
  for (int i = 1; i < 7; ++i) m = fmaxf(m, sreg[i]);
  m = fmaxf(m, __shfl_xor(m, 32));
  if ((u & 32) == 0) pmax_s[w][p] = m;
  __syncthreads();                           // S1: k reads done, pmax ready
  m = fmaxf(fmaxf(pmax_s[0][p], pmax_s[1][p]),
            fmaxf(pmax_s[2][p], pmax_s[3][p]));

  float e[7];
  float sl = 0.f;
#pragma unroll
  for (int i = 0; i < 7; ++i) { e[i] = __expf(sreg[i] - m); sl += e[i]; }
  sl += __shfl_xor(sl, 32);
  if ((u & 32) == 0) psum_s[w][p] = sl;

  // ---- stage v into dead k buffer: row t -> kv4[t*33 + c4] ----------------
  for (int i = u; i < K2 * 32; i += 256) {
    int tp = i >> 5, c4 = i & 31;
    int th = tp / KS, tw = tp - th * KS;
    kv4[tp * KQV + c4] =
        *(const float4*)&vt[(size_t)((sh + th) * WK + (sw + tw)) * C_V + c4 * 4];
  }
  __syncthreads();                           // S2: psum + v ready

  const float sum = psum_s[0][p] + psum_s[1][p] + psum_s[2][p] + psum_s[3][p];
  const float rinv = 1.f / (8.f * sum);

  // head-mean over h via shfl; lane h==0 writes pm
#pragma unroll
  for (int i = 0; i < 7; ++i) {
    float pv = e[i] * rinv;
    pv += __shfl_xor(pv, 1);
    pv += __shfl_xor(pv, 2);
    pv += __shfl_xor(pv, 4);
    const int t = r + 8 * i;
    if (h == 0 && t < K2) pm_s[qi * 52 + t] = pv;
  }
  __syncthreads();                           // S3: pm ready

  // ---- PV: wave = query, lane = float2 channel slot, v from LDS -----------
  const int qi2 = w;
  const int l   = u & 63;
  const int qx2 = 2 * a + (qi2 >> 1), qy2 = 2 * b + (qi2 & 1);
  const float2* v2 = (const float2*)kv_s;    // row pitch 66 float2
  float ax = 0.f, ay = 0.f;
#pragma unroll 7
  for (int t = 0; t < K2; ++t) {
    const float pm = pm_s[qi2 * 52 + t];
    const float2 vv = v2[t * (KQV * 2) + l];
    ax += pm * vv.x;
    ay += pm * vv.y;
  }
  const int posq = qx2 * WQ + qy2;
  out[(size_t)(2 * l + 0) * NPOS_Q + posq] = ax;
  out[(size_t)(2 * l + 1) * NPOS_Q + posq] = ay;
}

// ---------------------------------------------------------------------------
extern "C" void kernel_launch(void* const* d_in, const int* in_sizes, int n_in,
                              void* d_out, int out_size, void* d_ws, size_t ws_size,
                              hipStream_t stream) {
  const float* q   = (const float*)d_in[0];
  const float* k   = (const float*)d_in[1];
  const float* v   = (const float*)d_in[2];
  const float* w_q = (const float*)d_in[3];
  const float* b_q = (const float*)d_in[4];
  const float* w_k = (const float*)d_in[5];
  const float* b_k = (const float*)d_in[6];
  float* out = (float*)d_out;

  float* qt = (float*)d_ws;                  // [9216][256]
  float* kt = qt + (size_t)NPOS_Q * C_IN;    // [2304][256]
  float* vt = kt + (size_t)NPOS_K * C_IN;    // [2304][128]

  proj_gemm<<<dim3(TQ2 + TK2, 4), 256, 0, stream>>>(q, k, w_q, w_k, b_q, b_k, qt, kt);
  transpose_v<<<NPOS_K / 64, 256, 0, stream>>>(v, vt);
  natten_attn<<<dim3(HQ / 2, WQ / 2), 256, 0, stream>>>(qt, kt, vt, out);
}

// Round 7
// 68.696 us; speedup vs baseline: 1.7411x; 1.0715x over previous
//
#include <hip/hip_runtime.h>
#include <stdint.h>

// ---------------------------------------------------------------------------
// NATTEN cross attention, MI355X round 7: async global_load_lds everywhere.
// Window identity: key/value tap for query (x,y) =
//   (clip(x/2-3,0,41)+th, clip(y/2-3,0,41)+tw) in the native 48x48 grid.
// v7: attn = wave-per-query, ONE barrier; k/v staged via global_load_lds
//     (pre-swizzled per-lane global source, linear LDS dest); softmax and
//     head-mean fully in-wave (shfl over r=bits0-2 / h=bits3-5).
//     proj = 64x64 tile, KC=32, x via global_load_lds issued a chunk ahead,
//     w prefetched 2 chunks ahead; 720 blocks, 4 blocks/CU.
// ---------------------------------------------------------------------------

#define C_IN   256
#define C_V    128
#define HQ     96
#define WQ     96
#define HK     48
#define WK     48
#define NPOS_Q (HQ*WQ)    // 9216
#define NPOS_K (HK*WK)    // 2304
#define NH     8
#define DH     32
#define KS     7
#define K2     49

#define TQ3 (NPOS_Q/64)   // 144 M-tiles (Q proj)
#define TK3 (NPOS_K/64)   // 36  M-tiles (K proj)

#define VOFF 12544        // float offset of v region in kv_s (49*256)

// async global->LDS DMA, 16 B/lane, lane l lands at lds_base + 16*l
#define GLD(gp, lp) __builtin_amdgcn_global_load_lds(                      \
    (const __attribute__((address_space(1))) void*)(uintptr_t)(gp),        \
    (__attribute__((address_space(3))) void*)(uintptr_t)(lp), 16, 0, 0)

// ---- fused dual projection GEMM -------------------------------------------
// out_t[pos][o] = b[o] + sum_c w[o][c] * x[c][pos]
// 64x64 tile, KC=32, 256 threads, 4x4 acc, double-buffered, x via DMA.
__global__ __launch_bounds__(256) void proj_gemm(
    const float* __restrict__ xq, const float* __restrict__ xk,
    const float* __restrict__ wq, const float* __restrict__ wk,
    const float* __restrict__ bq, const float* __restrict__ bk,
    float* __restrict__ qt, float* __restrict__ kt) {
  __shared__ float xs[2][32][64];    // linear rows (DMA dest), reads conflict-free
  __shared__ float ws[2][32][68];

  const int mb = blockIdx.x;
  const float* x; const float* w; const float* bias; float* outp;
  int npos, m0;
  if (mb < TQ3) { x = xq; w = wq; bias = bq; outp = qt; npos = NPOS_Q; m0 = mb * 64; }
  else          { x = xk; w = wk; bias = bk; outp = kt; npos = NPOS_K; m0 = (mb - TQ3) * 64; }
  const int n0 = blockIdx.y * 64;

  const int t  = threadIdx.x;
  const int l  = t & 63;
  const int wv = t >> 6;
  const int tm = t & 15;           // m-frag rows tm*4..+3
  const int tn = t >> 4;           // n-frag cols tn*4..+3
  const int wo = t >> 2;           // w staging: output row 0..63
  const int wc = (t & 3) * 8;      // w staging: 8 c's per thread

  float acc[4][4];
#pragma unroll
  for (int i = 0; i < 4; ++i)
#pragma unroll
    for (int j = 0; j < 4; ++j) acc[i][j] = 0.f;

  // x DMA: 2 instrs/wave/chunk, each stages 4 rows x 64 floats (1 KB linear)
  #define STAGE_X(c0, p) do {                                               \
    _Pragma("unroll")                                                       \
    for (int s2 = 0; s2 < 2; ++s2) {                                        \
      const int row_ = wv * 8 + s2 * 4;                                     \
      GLD(x + (size_t)((c0) + row_ + (l >> 4)) * npos + m0 + (l & 15) * 4,  \
          &xs[p][row_][0]);                                                 \
    }                                                                       \
  } while (0)

  float4 wa0, wb0, wa1, wb1;
  STAGE_X(0, 0);
  wa0 = *(const float4*)&w[(size_t)(n0 + wo) * C_IN + 0 + wc];
  wb0 = *(const float4*)&w[(size_t)(n0 + wo) * C_IN + 0 + wc + 4];
  ws[0][wc + 0][wo] = wa0.x; ws[0][wc + 1][wo] = wa0.y;
  ws[0][wc + 2][wo] = wa0.z; ws[0][wc + 3][wo] = wa0.w;
  ws[0][wc + 4][wo] = wb0.x; ws[0][wc + 5][wo] = wb0.y;
  ws[0][wc + 6][wo] = wb0.z; ws[0][wc + 7][wo] = wb0.w;
  wa1 = *(const float4*)&w[(size_t)(n0 + wo) * C_IN + 32 + wc];
  wb1 = *(const float4*)&w[(size_t)(n0 + wo) * C_IN + 32 + wc + 4];
  __syncthreads();                    // chunk0 LDS ready

  for (int c = 0; c < 8; ++c) {
    const int cur = c & 1;
    if (c + 1 < 8) {
      STAGE_X((c + 1) * 32, cur ^ 1);          // buf cur^1 free since last barrier
      ws[cur ^ 1][wc + 0][wo] = wa1.x; ws[cur ^ 1][wc + 1][wo] = wa1.y;
      ws[cur ^ 1][wc + 2][wo] = wa1.z; ws[cur ^ 1][wc + 3][wo] = wa1.w;
      ws[cur ^ 1][wc + 4][wo] = wb1.x; ws[cur ^ 1][wc + 5][wo] = wb1.y;
      ws[cur ^ 1][wc + 6][wo] = wb1.z; ws[cur ^ 1][wc + 7][wo] = wb1.w;
      if (c + 2 < 8) {
        wa1 = *(const float4*)&w[(size_t)(n0 + wo) * C_IN + (c + 2) * 32 + wc];
        wb1 = *(const float4*)&w[(size_t)(n0 + wo) * C_IN + (c + 2) * 32 + wc + 4];
      }
    }
#pragma unroll
    for (int kk = 0; kk < 32; ++kk) {
      const float4 a4 = *(const float4*)&xs[cur][kk][tm * 4];
      const float4 b4 = *(const float4*)&ws[cur][kk][tn * 4];
      const float av[4] = {a4.x, a4.y, a4.z, a4.w};
      const float bv[4] = {b4.x, b4.y, b4.z, b4.w};
#pragma unroll
      for (int i = 0; i < 4; ++i)
#pragma unroll
        for (int j = 0; j < 4; ++j) acc[i][j] += av[i] * bv[j];
    }
    __syncthreads();                  // drains DMA(c+1) + w loads; ends reads of cur
  }

  const float4 bias4 = *(const float4*)&bias[n0 + tn * 4];
#pragma unroll
  for (int i = 0; i < 4; ++i) {
    float4 vv;
    vv.x = acc[i][0] + bias4.x;
    vv.y = acc[i][1] + bias4.y;
    vv.z = acc[i][2] + bias4.z;
    vv.w = acc[i][3] + bias4.w;
    *(float4*)&outp[(size_t)(m0 + tm * 4 + i) * C_IN + n0 + tn * 4] = vv;
  }
  #undef STAGE_X
}

// ---- v transpose: vt[pos][c] = v[c][pos] ----------------------------------
__global__ __launch_bounds__(256) void transpose_v(
    const float* __restrict__ v, float* __restrict__ vt) {
  __shared__ float tile[C_V * 65];
  const int p0 = blockIdx.x * 64;
  const int u  = threadIdx.x;
  for (int i = u; i < C_V * 64; i += 256) {
    int c = i >> 6, p = i & 63;
    tile[c * 65 + p] = v[c * NPOS_K + p0 + p];
  }
  __syncthreads();
  for (int i = u; i < C_V * 64; i += 256) {
    int p = i >> 7, c = i & 127;
    vt[(p0 + p) * C_V + c] = tile[c * 65 + p];
  }
}

// ---- fused neighborhood attention (wave-per-query, one barrier) -----------
// block = 256 threads = 2x2 query tile; wave w owns query (2a+(w>>1), 2b+(w&1)).
// Lane l: h = l>>3 (head), r = l&7 (tap residue); taps t = r+8i, i<7.
// k staged swizzled: LDS quad t*64 + j*8 + (h^j^(t&7)) holds k[row t][h*32+j*4..]
// via per-lane pre-swizzled DMA source (linear LDS dest). v rows linear.
__global__ __launch_bounds__(256) void natten_attn(
    const float* __restrict__ qt, const float* __restrict__ kt,
    const float* __restrict__ vt, float* __restrict__ out) {
  __shared__ float kv_s[K2 * 256 + 52 * 128];   // k: 49x256f, v: 52x128f
  __shared__ float pm_s[4][52];

  const int u  = threadIdx.x;
  const int a  = blockIdx.x;               // 0..47
  const int b  = blockIdx.y;               // 0..47
  const int sh = min(max(a - 3, 0), HK - KS);
  const int sw = min(max(b - 3, 0), WK - KS);

  const int l = u & 63;
  const int w = u >> 6;                    // wave = query index in 2x2 tile
  const int h = l >> 3;                    // head (bits 3..5)
  const int r = l & 7;                     // tap residue (bits 0..2)

  // ---- async k stage: rows t = w, w+4, ... (12-13 DMA/wave, all in flight)
  // dest quad (within row) = l = j*8+c; want it to hold source quad hh*8+j
  // with c = hh^j^(t&7)  =>  hh = (l&7) ^ (l>>3) ^ (t&7).
  for (int tp = w; tp < K2; tp += 4) {
    const int th = tp / KS, tw = tp - th * KS;
    const float* rowp = kt + (size_t)((sh + th) * WK + (sw + tw)) * C_IN;
    const int hh = r ^ h ^ (tp & 7);       // r==l&7, h==l>>3 here
    GLD(rowp + (hh * 8 + h) * 4, &kv_s[tp * 256]);
  }
  // ---- async v stage: row pairs (2s, 2s+1), s = w, w+4, ..., s<26 ----------
  // s=24,25 clamp to row 48 (fills pad rows 49..51 with finite data).
  for (int s = w; s < 26; s += 4) {
    const int row = min(2 * s + (l >> 5), K2 - 1);
    const int th = row / KS, tw = row - th * KS;
    GLD(vt + (size_t)((sh + th) * WK + (sw + tw)) * C_V + (l & 31) * 4,
        &kv_s[VOFF + s * 256]);
  }
  // ---- q slice (h) for this wave's query: 32 floats in registers ----------
  const int qx = 2 * a + (w >> 1), qy = 2 * b + (w & 1);
  const float4* q4 = (const float4*)&qt[(size_t)(qx * WQ + qy) * C_IN + h * DH];
  float4 qv[8];
#pragma unroll
  for (int j = 0; j < 8; ++j) qv[j] = q4[j];

  __syncthreads();                         // ONLY barrier: all DMA drained

  // ---- logits: taps t = r + 8i, k from LDS --------------------------------
  const float scale = 0.17677669529663687f;  // 32^-0.5
  const float4* k4 = (const float4*)kv_s;
  float sreg[7];
#pragma unroll
  for (int i = 0; i < 7; ++i) {
    const int tp = r + 8 * i;
    const int tc = min(tp, K2 - 1);
    const int base = tc * 64;
    const int hx = h ^ (tc & 7);
    float s = 0.f;
#pragma unroll
    for (int j = 0; j < 8; ++j) {
      const float4 kv = k4[base + j * 8 + (hx ^ j)];
      s += qv[j].x * kv.x + qv[j].y * kv.y + qv[j].z * kv.z + qv[j].w * kv.w;
    }
    sreg[i] = (tp < K2) ? s * scale : -1e30f;
  }

  // ---- softmax per (query,head): reduce over r = lane bits 0..2 (shfl only)
  float m = sreg[0];
#pragma unroll
  for (int i = 1; i < 7; ++i) m = fmaxf(m, sreg[i]);
  m = fmaxf(m, __shfl_xor(m, 1));
  m = fmaxf(m, __shfl_xor(m, 2));
  m = fmaxf(m, __shfl_xor(m, 4));
  float e[7];
  float sl = 0.f;
#pragma unroll
  for (int i = 0; i < 7; ++i) { e[i] = __expf(sreg[i] - m); sl += e[i]; }
  sl += __shfl_xor(sl, 1);
  sl += __shfl_xor(sl, 2);
  sl += __shfl_xor(sl, 4);
  const float rinv = 1.f / (8.f * sl);

  // ---- head-mean over h = lane bits 3..5; lanes h==0 write pm (wave-private)
#pragma unroll
  for (int i = 0; i < 7; ++i) {
    float pv = e[i] * rinv;
    pv += __shfl_xor(pv, 8);
    pv += __shfl_xor(pv, 16);
    pv += __shfl_xor(pv, 32);
    const int tp = r + 8 * i;
    if (h == 0 && tp < K2) pm_s[w][tp] = pv;
  }
  if (l == 0) { pm_s[w][49] = 0.f; pm_s[w][50] = 0.f; pm_s[w][51] = 0.f; }

  // ---- PV: lane = float2 channel slot, v + pm from LDS (same wave, no bar)
  const float2* v2 = (const float2*)&kv_s[VOFF];
  float ax = 0.f, ay = 0.f;
#pragma unroll
  for (int t0 = 0; t0 < 52; t0 += 4) {
    const float4 pm4 = *(const float4*)&pm_s[w][t0];
    const float2 vv0 = v2[(t0 + 0) * 64 + l];
    const float2 vv1 = v2[(t0 + 1) * 64 + l];
    const float2 vv2 = v2[(t0 + 2) * 64 + l];
    const float2 vv3 = v2[(t0 + 3) * 64 + l];
    ax += pm4.x * vv0.x + pm4.y * vv1.x + pm4.z * vv2.x + pm4.w * vv3.x;
    ay += pm4.x * vv0.y + pm4.y * vv1.y + pm4.z * vv2.y + pm4.w * vv3.y;
  }
  const int posq = qx * WQ + qy;
  out[(size_t)(2 * l + 0) * NPOS_Q + posq] = ax;
  out[(size_t)(2 * l + 1) * NPOS_Q + posq] = ay;
}

// ---------------------------------------------------------------------------
extern "C" void kernel_launch(void* const* d_in, const int* in_sizes, int n_in,
                              void* d_out, int out_size, void* d_ws, size_t ws_size,
                              hipStream_t stream) {
  const float* q   = (const float*)d_in[0];
  const float* k   = (const float*)d_in[1];
  const float* v   = (const float*)d_in[2];
  const float* w_q = (const float*)d_in[3];
  const float* b_q = (const float*)d_in[4];
  const float* w_k = (const float*)d_in[5];
  const float* b_k = (const float*)d_in[6];
  float* out = (float*)d_out;

  float* qt = (float*)d_ws;                  // [9216][256]
  float* kt = qt + (size_t)NPOS_Q * C_IN;    // [2304][256]
  float* vt = kt + (size_t)NPOS_K * C_IN;    // [2304][128]

  proj_gemm<<<dim3(TQ3 + TK3, 4), 256, 0, stream>>>(q, k, w_q, w_k, b_q, b_k, qt, kt);
  transpose_v<<<NPOS_K / 64, 256, 0, stream>>>(v, vt);
  natten_attn<<<dim3(HQ / 2, WQ / 2), 256, 0, stream>>>(qt, kt, vt, out);
}

// Round 8
// 57.270 us; speedup vs baseline: 2.0885x; 1.1995x over previous
//
#include <hip/hip_runtime.h>
#include <hip/hip_fp16.h>
#include <stdint.h>

// ---------------------------------------------------------------------------
// NATTEN cross attention, MI355X round 8.
// Window identity: key/value tap for query (x,y) =
//   (clip(x/2-3,0,41)+th, clip(y/2-3,0,41)+tw) in the native 48x48 grid.
// v8:
//  * proj: SGPR-broadcast GEMM. Old 4x4 f32 tile = 0.5 FMA per LDS byte ->
//    needs 256 B/cyc/CU vs ~112 available (LDS-BW-bound). Now lane = position,
//    o-tile 16 per wave: per kk ONE ds_read_b32 (x) + 16 v_fmac with the w
//    operand s_loaded from a pre-transposed wt[c][o] (wave-uniform). LDS
//    traffic ~0; purely VALU-bound. 2880 waves = 2.8/SIMD.
//  * qt/kt/vt emitted as f16 -> attn LDS 77.6KB -> 42.9KB (3 blocks/CU),
//    LDS read bytes halved, logits via v_dot2_f32_f16 (16 dot2/tap).
//  * attn keeps round-7 wave-per-query + single barrier + GLD staging with
//    per-lane pre-swizzled global source (linear LDS dest).
// ---------------------------------------------------------------------------

#define C_IN   256
#define C_V    128
#define HQ     96
#define WQ     96
#define HK     48
#define WK     48
#define NPOS_Q (HQ*WQ)    // 9216
#define NPOS_K (HK*WK)    // 2304
#define NH     8
#define DH     32
#define KS     7
#define K2     49

// async global->LDS DMA, 16 B/lane, lane l lands at lds_base + 16*l
#define GLD(gp, lp) __builtin_amdgcn_global_load_lds(                      \
    (const __attribute__((address_space(1))) void*)(uintptr_t)(gp),        \
    (__attribute__((address_space(3))) void*)(uintptr_t)(lp), 16, 0, 0)

static __device__ __forceinline__ float dot2f(uint32_t a, uint32_t b, float c) {
#if __has_builtin(__builtin_amdgcn_fdot2)
  typedef _Float16 h2 __attribute__((ext_vector_type(2)));
  h2 ha = __builtin_bit_cast(h2, a);
  h2 hb = __builtin_bit_cast(h2, b);
  return __builtin_amdgcn_fdot2(ha, hb, c, false);
#else
  const __half2 ha = *reinterpret_cast<const __half2*>(&a);
  const __half2 hb = *reinterpret_cast<const __half2*>(&b);
  const float2 fa = __half22float2(ha);
  const float2 fb = __half22float2(hb);
  return c + fa.x * fb.x + fa.y * fb.y;
#endif
}

// ---- prep: vt_h[pos][c] = (half)v[c][pos]; wt[c][o] = w[o][c] --------------
// blocks 0..35: v transpose+cvt (64 pos each). blocks 36..67: w transposes
// (16 tiles of 64x64 each for w_q then w_k).
__global__ __launch_bounds__(256) void prep(
    const float* __restrict__ v, const float* __restrict__ wq,
    const float* __restrict__ wk, __half* __restrict__ vt,
    float* __restrict__ wtq, float* __restrict__ wtk) {
  __shared__ float tile[128 * 65];
  const int bid = blockIdx.x;
  const int u = threadIdx.x;
  if (bid < 36) {
    const int p0 = bid * 64;
    for (int i = u; i < 128 * 64; i += 256) {
      int c = i >> 6, p = i & 63;
      tile[c * 65 + p] = v[(size_t)c * NPOS_K + p0 + p];
    }
    __syncthreads();
    uint32_t* vo = (uint32_t*)vt;
    for (int i = u; i < 64 * 64; i += 256) {
      int p = i >> 6, c2 = (i & 63) * 2;
      __half2 hv = __floats2half2_rn(tile[c2 * 65 + p], tile[(c2 + 1) * 65 + p]);
      vo[(size_t)(p0 + p) * 64 + (i & 63)] = *reinterpret_cast<uint32_t*>(&hv);
    }
  } else {
    const int wb = bid - 36;
    const float* src = (wb < 16) ? wq : wk;
    float* dst = (wb < 16) ? wtq : wtk;
    const int ti = wb & 15;
    const int r0 = (ti >> 2) * 64, c0 = (ti & 3) * 64;
    for (int i = u; i < 64 * 64; i += 256) {
      int ol = i >> 6, cl = i & 63;
      tile[cl * 65 + ol] = src[(size_t)(r0 + ol) * C_IN + c0 + cl];
    }
    __syncthreads();
    for (int i = u; i < 64 * 64; i += 256) {
      int cl = i >> 6, ol = i & 63;
      dst[(size_t)(c0 + cl) * C_IN + r0 + ol] = tile[cl * 65 + ol];
    }
  }
}

// ---- SGPR-broadcast projection: out_h[pos][o] = (half)(b[o]+sum w[o][c]x[c][pos])
// block 256 thr = 4 waves; lane = pos (64-pos tile); wave o-tile 16.
// grid (180, 4): mb<144 -> Q (pos tile mb), else K. blockIdx.y*64+wid*16 = o0.
__global__ __launch_bounds__(256) void proj_gemm(
    const float* __restrict__ xq, const float* __restrict__ xk,
    const float* __restrict__ wtq, const float* __restrict__ wtk,
    const float* __restrict__ bq, const float* __restrict__ bk,
    __half* __restrict__ qo, __half* __restrict__ ko) {
  __shared__ float xs[2][64][64];    // [buf][kk][pos], GLD-staged, b32 reads

  const int mb = blockIdx.x;
  const float* x; const float* wt; const float* bias; __half* outp;
  int npos, m0;
  if (mb < 144) { x = xq; wt = wtq; bias = bq; outp = qo; npos = NPOS_Q; m0 = mb * 64; }
  else          { x = xk; wt = wtk; bias = bk; outp = ko; npos = NPOS_K; m0 = (mb - 144) * 64; }

  const int u   = threadIdx.x;
  const int l   = u & 63;
  const int wid = __builtin_amdgcn_readfirstlane(u >> 6);
  const int o0  = blockIdx.y * 64 + wid * 16;

  float acc[16];
#pragma unroll
  for (int j = 0; j < 16; ++j) acc[j] = 0.f;

  // stage one 64-kk chunk: 16 GLD (4 per wave), 4 kk-rows each, linear
#define STAGE(c0_, p_)                                                        \
  for (int g = wid; g < 16; g += 4)                                           \
    GLD(x + (size_t)((c0_) + g * 4 + (l >> 4)) * npos + m0 + (l & 15) * 4,    \
        &xs[p_][g * 4][0])

  STAGE(0, 0);
  __syncthreads();

  for (int ch = 0; ch < 4; ++ch) {
    const int cur = ch & 1;
    if (ch < 3) STAGE((ch + 1) * 64, cur ^ 1);
    const float* wbase = wt + (size_t)ch * 64 * C_IN + o0;
#pragma unroll 8
    for (int kk = 0; kk < 64; ++kk) {
      const float xv = xs[cur][kk][l];
      const float4* w4 = (const float4*)(wbase + (size_t)kk * C_IN);
      const float4 w0 = w4[0], w1 = w4[1], w2 = w4[2], w3 = w4[3];
      acc[0]  += w0.x * xv; acc[1]  += w0.y * xv;
      acc[2]  += w0.z * xv; acc[3]  += w0.w * xv;
      acc[4]  += w1.x * xv; acc[5]  += w1.y * xv;
      acc[6]  += w1.z * xv; acc[7]  += w1.w * xv;
      acc[8]  += w2.x * xv; acc[9]  += w2.y * xv;
      acc[10] += w2.z * xv; acc[11] += w2.w * xv;
      acc[12] += w3.x * xv; acc[13] += w3.y * xv;
      acc[14] += w3.z * xv; acc[15] += w3.w * xv;
    }
    __syncthreads();   // drains DMA for next chunk; ends reads of cur
  }
#undef STAGE

  const float4 b0 = *(const float4*)&bias[o0];
  const float4 b1 = *(const float4*)&bias[o0 + 4];
  const float4 b2 = *(const float4*)&bias[o0 + 8];
  const float4 b3 = *(const float4*)&bias[o0 + 12];
  const float bb[16] = {b0.x, b0.y, b0.z, b0.w, b1.x, b1.y, b1.z, b1.w,
                        b2.x, b2.y, b2.z, b2.w, b3.x, b3.y, b3.z, b3.w};
  uint32_t pk[8];
#pragma unroll
  for (int j = 0; j < 8; ++j) {
    __half2 hv = __floats2half2_rn(acc[2 * j] + bb[2 * j], acc[2 * j + 1] + bb[2 * j + 1]);
    pk[j] = *reinterpret_cast<uint32_t*>(&hv);
  }
  uint32_t* op = (uint32_t*)(outp + (size_t)(m0 + l) * C_IN + o0);
  uint4 s0 = {pk[0], pk[1], pk[2], pk[3]};
  uint4 s1 = {pk[4], pk[5], pk[6], pk[7]};
  *(uint4*)op = s0;
  *(uint4*)(op + 4) = s1;
}

// ---- fused neighborhood attention (f16 k/v/q, wave-per-query, one barrier) -
// k LDS: 7 window rows x 8 taps x 512B, slot s (16B) of tap holds source
// chunk (s&7)*4 + (s>>3)  => read (h,j2) at slot j2*8+h => granule class = h.
// v LDS: 52 taps x 256B linear. Lane l: h=l>>3, r=l&7; taps t=r+8i.
__global__ __launch_bounds__(256) void natten_attn(
    const __half* __restrict__ qt, const __half* __restrict__ kt,
    const __half* __restrict__ vt, float* __restrict__ out) {
  __shared__ uint32_t k_s[7168];            // 28672 B
  __shared__ uint32_t v_s[3328];            // 13312 B
  __shared__ float pm_s[4][52];

  const int u  = threadIdx.x;
  const int a  = blockIdx.x;               // 0..47
  const int b  = blockIdx.y;               // 0..47
  const int sh = min(max(a - 3, 0), HK - KS);
  const int sw = min(max(b - 3, 0), WK - KS);

  const int l = u & 63;
  const int w = __builtin_amdgcn_readfirstlane(u >> 6);  // wave = query
  const int h = l >> 3;
  const int r = l & 7;

  // ---- k DMA: 28 instrs; instr (th,g) covers taps g*2,g*2+1 of window row th
  for (int idx = w; idx < 28; idx += 4) {
    const int th = idx >> 2, g = idx & 3;
    const int tapcol = g * 2 + (l >> 5);
    const int slot = l & 31;
    const int csrc = (slot & 7) * 4 + (slot >> 3);
    const __half* src =
        kt + (size_t)((sh + th) * WK + sw + tapcol) * C_IN + csrc * 8;
    GLD(src, (char*)k_s + th * 4096 + g * 1024);
  }
  // ---- v DMA: 13 instrs; instr idx covers taps 4idx..4idx+3 (clamped), linear
  for (int idx = w; idx < 13; idx += 4) {
    const int tap = min(idx * 4 + (l >> 4), K2 - 1);
    const int th = tap / KS, tw = tap - th * KS;
    const __half* src =
        vt + (size_t)((sh + th) * WK + sw + tw) * C_V + (l & 15) * 8;
    GLD(src, (char*)v_s + idx * 1024);
  }
  // ---- q slice (f16 pairs) for this wave's query ---------------------------
  const int qx = 2 * a + (w >> 1), qy = 2 * b + (w & 1);
  const uint4* qp = (const uint4*)(qt + (size_t)(qx * WQ + qy) * C_IN + h * DH);
  const uint4 qa = qp[0], qb = qp[1], qc = qp[2], qd = qp[3];
  const uint32_t q16[16] = {qa.x, qa.y, qa.z, qa.w, qb.x, qb.y, qb.z, qb.w,
                            qc.x, qc.y, qc.z, qc.w, qd.x, qd.y, qd.z, qd.w};

  __syncthreads();                         // ONLY barrier: all DMA drained

  // ---- logits: taps t = r + 8i ---------------------------------------------
  const float scale = 0.17677669529663687f;  // 32^-0.5
  float sreg[7];
#pragma unroll
  for (int i = 0; i < 7; ++i) {
    const int t = r + 8 * i;
    const int tc = min(t, K2 - 1);
    const int th = tc / KS, tw = tc - th * KS;
    const uint32_t* krow = k_s + th * 1024 + tw * 128 + h * 4;
    float s = 0.f;
#pragma unroll
    for (int j2 = 0; j2 < 4; ++j2) {
      const uint4 kv = *(const uint4*)(krow + j2 * 32);
      s = dot2f(kv.x, q16[j2 * 4 + 0], s);
      s = dot2f(kv.y, q16[j2 * 4 + 1], s);
      s = dot2f(kv.z, q16[j2 * 4 + 2], s);
      s = dot2f(kv.w, q16[j2 * 4 + 3], s);
    }
    sreg[i] = (t < K2) ? s * scale : -1e30f;
  }

  // ---- softmax per (query,head): reduce over r = lane bits 0..2 ------------
  float m = sreg[0];
#pragma unroll
  for (int i = 1; i < 7; ++i) m = fmaxf(m, sreg[i]);
  m = fmaxf(m, __shfl_xor(m, 1));
  m = fmaxf(m, __shfl_xor(m, 2));
  m = fmaxf(m, __shfl_xor(m, 4));
  float e[7];
  float sl = 0.f;
#pragma unroll
  for (int i = 0; i < 7; ++i) { e[i] = __expf(sreg[i] - m); sl += e[i]; }
  sl += __shfl_xor(sl, 1);
  sl += __shfl_xor(sl, 2);
  sl += __shfl_xor(sl, 4);
  const float rinv = 1.f / (8.f * sl);

  // ---- head-mean over h = lane bits 3..5; lanes h==0 write pm (wave-private)
#pragma unroll
  for (int i = 0; i < 7; ++i) {
    float pv = e[i] * rinv;
    pv += __shfl_xor(pv, 8);
    pv += __shfl_xor(pv, 16);
    pv += __shfl_xor(pv, 32);
    const int t = r + 8 * i;
    if (h == 0 && t < K2) pm_s[w][t] = pv;
  }
  if (l == 0) { pm_s[w][49] = 0.f; pm_s[w][50] = 0.f; pm_s[w][51] = 0.f; }

  // ---- PV: lane = 2-channel slot, v f16 from LDS (b32, conflict-free) ------
  float ax = 0.f, ay = 0.f;
#pragma unroll
  for (int t0 = 0; t0 < 52; t0 += 4) {
    const float4 pm4 = *(const float4*)&pm_s[w][t0];
    const uint32_t v0 = v_s[(t0 + 0) * 64 + l];
    const uint32_t v1 = v_s[(t0 + 1) * 64 + l];
    const uint32_t v2 = v_s[(t0 + 2) * 64 + l];
    const uint32_t v3 = v_s[(t0 + 3) * 64 + l];
    const float2 f0 = __half22float2(*(const __half2*)&v0);
    const float2 f1 = __half22float2(*(const __half2*)&v1);
    const float2 f2 = __half22float2(*(const __half2*)&v2);
    const float2 f3 = __half22float2(*(const __half2*)&v3);
    ax += pm4.x * f0.x + pm4.y * f1.x + pm4.z * f2.x + pm4.w * f3.x;
    ay += pm4.x * f0.y + pm4.y * f1.y + pm4.z * f2.y + pm4.w * f3.y;
  }
  const int posq = qx * WQ + qy;
  out[(size_t)(2 * l + 0) * NPOS_Q + posq] = ax;
  out[(size_t)(2 * l + 1) * NPOS_Q + posq] = ay;
}

// ---------------------------------------------------------------------------
extern "C" void kernel_launch(void* const* d_in, const int* in_sizes, int n_in,
                              void* d_out, int out_size, void* d_ws, size_t ws_size,
                              hipStream_t stream) {
  const float* q   = (const float*)d_in[0];
  const float* k   = (const float*)d_in[1];
  const float* v   = (const float*)d_in[2];
  const float* w_q = (const float*)d_in[3];
  const float* b_q = (const float*)d_in[4];
  const float* w_k = (const float*)d_in[5];
  const float* b_k = (const float*)d_in[6];
  float* out = (float*)d_out;

  float* wtq = (float*)d_ws;                       // [256][256]
  float* wtk = wtq + 65536;                        // [256][256]
  __half* qt_h = (__half*)(wtk + 65536);           // [9216][256]
  __half* kt_h = qt_h + (size_t)NPOS_Q * C_IN;     // [2304][256]
  __half* vt_h = kt_h + (size_t)NPOS_K * C_IN;     // [2304][128]

  prep<<<68, 256, 0, stream>>>(v, w_q, w_k, vt_h, wtq, wtk);
  proj_gemm<<<dim3(180, 4), 256, 0, stream>>>(q, k, wtq, wtk, b_q, b_k, qt_h, kt_h);
  natten_attn<<<dim3(HQ / 2, WQ / 2), 256, 0, stream>>>(qt_h, kt_h, vt_h, out);
}

// Round 9
// 56.883 us; speedup vs baseline: 2.1027x; 1.0068x over previous
//
#include <hip/hip_runtime.h>
#include <hip/hip_fp16.h>
#include <stdint.h>

// ---------------------------------------------------------------------------
// NATTEN cross attention, MI355X round 9.
// Window identity: key/value tap for query (x,y) =
//   (clip(x/2-3,0,41)+th, clip(y/2-3,0,41)+tw) in the native 48x48 grid.
// v9 (attn only; prep/proj identical to r8):
//   attn tile 2x2 -> 2x4 queries per block. x-pair shares x/2 -> single sh;
//   y-quad spans y/2 in {2b,2b+1} -> stage 7x8 window rows, per-query col
//   offset dl in {0,1}. Per-CU staging DMA and barrier-drains HALVE while
//   logits/PV work is unchanged. Grid 1152 blocks, LDS 43.6KB, 3 blocks/CU.
// ---------------------------------------------------------------------------

#define C_IN   256
#define C_V    128
#define HQ     96
#define WQ     96
#define HK     48
#define WK     48
#define NPOS_Q (HQ*WQ)    // 9216
#define NPOS_K (HK*WK)    // 2304
#define NH     8
#define DH     32
#define KS     7
#define K2     49

// async global->LDS DMA, 16 B/lane, lane l lands at lds_base + 16*l
#define GLD(gp, lp) __builtin_amdgcn_global_load_lds(                      \
    (const __attribute__((address_space(1))) void*)(uintptr_t)(gp),        \
    (__attribute__((address_space(3))) void*)(uintptr_t)(lp), 16, 0, 0)

static __device__ __forceinline__ float dot2f(uint32_t a, uint32_t b, float c) {
#if __has_builtin(__builtin_amdgcn_fdot2)
  typedef _Float16 h2 __attribute__((ext_vector_type(2)));
  h2 ha = __builtin_bit_cast(h2, a);
  h2 hb = __builtin_bit_cast(h2, b);
  return __builtin_amdgcn_fdot2(ha, hb, c, false);
#else
  const __half2 ha = *reinterpret_cast<const __half2*>(&a);
  const __half2 hb = *reinterpret_cast<const __half2*>(&b);
  const float2 fa = __half22float2(ha);
  const float2 fb = __half22float2(hb);
  return c + fa.x * fb.x + fa.y * fb.y;
#endif
}

// ---- prep: vt_h[pos][c] = (half)v[c][pos]; wt[c][o] = w[o][c] --------------
__global__ __launch_bounds__(256) void prep(
    const float* __restrict__ v, const float* __restrict__ wq,
    const float* __restrict__ wk, __half* __restrict__ vt,
    float* __restrict__ wtq, float* __restrict__ wtk) {
  __shared__ float tile[128 * 65];
  const int bid = blockIdx.x;
  const int u = threadIdx.x;
  if (bid < 36) {
    const int p0 = bid * 64;
    for (int i = u; i < 128 * 64; i += 256) {
      int c = i >> 6, p = i & 63;
      tile[c * 65 + p] = v[(size_t)c * NPOS_K + p0 + p];
    }
    __syncthreads();
    uint32_t* vo = (uint32_t*)vt;
    for (int i = u; i < 64 * 64; i += 256) {
      int p = i >> 6, c2 = (i & 63) * 2;
      __half2 hv = __floats2half2_rn(tile[c2 * 65 + p], tile[(c2 + 1) * 65 + p]);
      vo[(size_t)(p0 + p) * 64 + (i & 63)] = *reinterpret_cast<uint32_t*>(&hv);
    }
  } else {
    const int wb = bid - 36;
    const float* src = (wb < 16) ? wq : wk;
    float* dst = (wb < 16) ? wtq : wtk;
    const int ti = wb & 15;
    const int r0 = (ti >> 2) * 64, c0 = (ti & 3) * 64;
    for (int i = u; i < 64 * 64; i += 256) {
      int ol = i >> 6, cl = i & 63;
      tile[cl * 65 + ol] = src[(size_t)(r0 + ol) * C_IN + c0 + cl];
    }
    __syncthreads();
    for (int i = u; i < 64 * 64; i += 256) {
      int cl = i >> 6, ol = i & 63;
      dst[(size_t)(c0 + cl) * C_IN + r0 + ol] = tile[cl * 65 + ol];
    }
  }
}

// ---- SGPR-broadcast projection (identical to r8) ---------------------------
__global__ __launch_bounds__(256) void proj_gemm(
    const float* __restrict__ xq, const float* __restrict__ xk,
    const float* __restrict__ wtq, const float* __restrict__ wtk,
    const float* __restrict__ bq, const float* __restrict__ bk,
    __half* __restrict__ qo, __half* __restrict__ ko) {
  __shared__ float xs[2][64][64];

  const int mb = blockIdx.x;
  const float* x; const float* wt; const float* bias; __half* outp;
  int npos, m0;
  if (mb < 144) { x = xq; wt = wtq; bias = bq; outp = qo; npos = NPOS_Q; m0 = mb * 64; }
  else          { x = xk; wt = wtk; bias = bk; outp = ko; npos = NPOS_K; m0 = (mb - 144) * 64; }

  const int u   = threadIdx.x;
  const int l   = u & 63;
  const int wid = __builtin_amdgcn_readfirstlane(u >> 6);
  const int o0  = blockIdx.y * 64 + wid * 16;

  float acc[16];
#pragma unroll
  for (int j = 0; j < 16; ++j) acc[j] = 0.f;

#define STAGE(c0_, p_)                                                        \
  for (int g = wid; g < 16; g += 4)                                           \
    GLD(x + (size_t)((c0_) + g * 4 + (l >> 4)) * npos + m0 + (l & 15) * 4,    \
        &xs[p_][g * 4][0])

  STAGE(0, 0);
  __syncthreads();

  for (int ch = 0; ch < 4; ++ch) {
    const int cur = ch & 1;
    if (ch < 3) STAGE((ch + 1) * 64, cur ^ 1);
    const float* wbase = wt + (size_t)ch * 64 * C_IN + o0;
#pragma unroll 8
    for (int kk = 0; kk < 64; ++kk) {
      const float xv = xs[cur][kk][l];
      const float4* w4 = (const float4*)(wbase + (size_t)kk * C_IN);
      const float4 w0 = w4[0], w1 = w4[1], w2 = w4[2], w3 = w4[3];
      acc[0]  += w0.x * xv; acc[1]  += w0.y * xv;
      acc[2]  += w0.z * xv; acc[3]  += w0.w * xv;
      acc[4]  += w1.x * xv; acc[5]  += w1.y * xv;
      acc[6]  += w1.z * xv; acc[7]  += w1.w * xv;
      acc[8]  += w2.x * xv; acc[9]  += w2.y * xv;
      acc[10] += w2.z * xv; acc[11] += w2.w * xv;
      acc[12] += w3.x * xv; acc[13] += w3.y * xv;
      acc[14] += w3.z * xv; acc[15] += w3.w * xv;
    }
    __syncthreads();
  }
#undef STAGE

  const float4 b0 = *(const float4*)&bias[o0];
  const float4 b1 = *(const float4*)&bias[o0 + 4];
  const float4 b2 = *(const float4*)&bias[o0 + 8];
  const float4 b3 = *(const float4*)&bias[o0 + 12];
  const float bb[16] = {b0.x, b0.y, b0.z, b0.w, b1.x, b1.y, b1.z, b1.w,
                        b2.x, b2.y, b2.z, b2.w, b3.x, b3.y, b3.z, b3.w};
  uint32_t pk[8];
#pragma unroll
  for (int j = 0; j < 8; ++j) {
    __half2 hv = __floats2half2_rn(acc[2 * j] + bb[2 * j], acc[2 * j + 1] + bb[2 * j + 1]);
    pk[j] = *reinterpret_cast<uint32_t*>(&hv);
  }
  uint32_t* op = (uint32_t*)(outp + (size_t)(m0 + l) * C_IN + o0);
  uint4 s0 = {pk[0], pk[1], pk[2], pk[3]};
  uint4 s1 = {pk[4], pk[5], pk[6], pk[7]};
  *(uint4*)op = s0;
  *(uint4*)(op + 4) = s1;
}

// ---- fused neighborhood attention: 2x4 query tile --------------------------
// Window region: rows sh..sh+6, cols sw0..sw0+7 (per-query col offset dl).
// k LDS: [7 rows][8 cols][512B], within-tap slot s holds source chunk
//   (s&7)*4+(s>>3) -> read (h,j2) at slot j2*8+h -> granule class = h.
// v LDS: 56 taps x 256B linear. Wave w owns queries w*2, w*2+1.
__global__ __launch_bounds__(256) void natten_attn(
    const __half* __restrict__ qt, const __half* __restrict__ kt,
    const __half* __restrict__ vt, float* __restrict__ out) {
  __shared__ uint32_t k_s[7168];            // 28672 B
  __shared__ uint32_t v_s[3584];            // 14336 B
  __shared__ float pm_s[8][52];             //  1664 B

  const int u  = threadIdx.x;
  const int a  = blockIdx.x;               // 0..47 : x-pair 2a..2a+1
  const int b  = blockIdx.y;               // 0..23 : y-quad 4b..4b+3
  const int sh  = min(max(a - 3, 0), HK - KS);
  const int sw0 = min(max(2 * b - 3, 0), WK - KS);
  const int sw1 = min(max(2 * b - 2, 0), WK - KS);
  const int dlt = sw1 - sw0;               // 0 or 1

  const int l = u & 63;
  const int w = __builtin_amdgcn_readfirstlane(u >> 6);
  const int h = l >> 3;
  const int r = l & 7;

  // ---- k DMA: 28 instrs; (th, col-pair) -> 1KB
  for (int idx = w; idx < 28; idx += 4) {
    const int th = idx >> 2, pr = idx & 3;
    const int col = min(sw0 + pr * 2 + (l >> 5), WK - 1);
    const int slot = l & 31;
    const int csrc = (slot & 7) * 4 + (slot >> 3);
    GLD(kt + (size_t)((sh + th) * WK + col) * C_IN + csrc * 8,
        (char*)k_s + th * 4096 + pr * 1024);
  }
  // ---- v DMA: 14 instrs; 4 region-taps each, linear
  for (int idx = w; idx < 14; idx += 4) {
    const int j = idx * 4 + (l >> 4);      // region tap 0..55 = th*8+cc
    const int col = min(sw0 + (j & 7), WK - 1);
    GLD(vt + (size_t)((sh + (j >> 3)) * WK + col) * C_V + (l & 15) * 8,
        (char*)v_s + idx * 1024);
  }
  // ---- q slices for both queries (f16 pairs), registers --------------------
  uint32_t q16[2][16];
#pragma unroll
  for (int qq = 0; qq < 2; ++qq) {
    const int qidx = w * 2 + qq;
    const int x = 2 * a + (qidx >> 2);
    const int y = 4 * b + (qidx & 3);
    const uint4* qp = (const uint4*)(qt + (size_t)(x * WQ + y) * C_IN + h * DH);
    const uint4 qa = qp[0], qb = qp[1], qc = qp[2], qd = qp[3];
    q16[qq][0]  = qa.x; q16[qq][1]  = qa.y; q16[qq][2]  = qa.z; q16[qq][3]  = qa.w;
    q16[qq][4]  = qb.x; q16[qq][5]  = qb.y; q16[qq][6]  = qb.z; q16[qq][7]  = qb.w;
    q16[qq][8]  = qc.x; q16[qq][9]  = qc.y; q16[qq][10] = qc.z; q16[qq][11] = qc.w;
    q16[qq][12] = qd.x; q16[qq][13] = qd.y; q16[qq][14] = qd.z; q16[qq][15] = qd.w;
  }

  __syncthreads();                         // ONLY barrier: all DMA drained

  const float scale = 0.17677669529663687f;  // 32^-0.5

  // ---- per-query logits + softmax + head-mean ------------------------------
#pragma unroll
  for (int qq = 0; qq < 2; ++qq) {
    const int qidx = w * 2 + qq;
    const int dl = (qidx & 2) ? dlt : 0;

    int th = (r == 7) ? 1 : 0;
    int tw = (r == 7) ? 0 : r;
    float sreg[7];
#pragma unroll
    for (int i = 0; i < 7; ++i) {
      const int t = r + 8 * i;
      const uint32_t* krow = k_s + (th * 8 + tw + dl) * 128 + h * 4;
      float s = 0.f;
#pragma unroll
      for (int j2 = 0; j2 < 4; ++j2) {
        const uint4 kv = *(const uint4*)(krow + j2 * 32);
        s = dot2f(kv.x, q16[qq][j2 * 4 + 0], s);
        s = dot2f(kv.y, q16[qq][j2 * 4 + 1], s);
        s = dot2f(kv.z, q16[qq][j2 * 4 + 2], s);
        s = dot2f(kv.w, q16[qq][j2 * 4 + 3], s);
      }
      sreg[i] = (t < K2) ? s * scale : -1e30f;
      tw += 1; th += 1;
      if (tw >= 7) { tw -= 7; th += 1; }   // advance tap by 8 in base-7
    }

    float m = sreg[0];
#pragma unroll
    for (int i = 1; i < 7; ++i) m = fmaxf(m, sreg[i]);
    m = fmaxf(m, __shfl_xor(m, 1));
    m = fmaxf(m, __shfl_xor(m, 2));
    m = fmaxf(m, __shfl_xor(m, 4));
    float e[7];
    float sl = 0.f;
#pragma unroll
    for (int i = 0; i < 7; ++i) { e[i] = __expf(sreg[i] - m); sl += e[i]; }
    sl += __shfl_xor(sl, 1);
    sl += __shfl_xor(sl, 2);
    sl += __shfl_xor(sl, 4);
    const float rinv = 1.f / (8.f * sl);

#pragma unroll
    for (int i = 0; i < 7; ++i) {
      float pv = e[i] * rinv;
      pv += __shfl_xor(pv, 8);
      pv += __shfl_xor(pv, 16);
      pv += __shfl_xor(pv, 32);
      const int t = r + 8 * i;
      if (h == 0 && t < K2) pm_s[qidx][t] = pv;
    }
  }

  // ---- PV per query: lane = 2-channel slot, compile-time tap rows ----------
#pragma unroll
  for (int qq = 0; qq < 2; ++qq) {
    const int qidx = w * 2 + qq;
    const int dl = (qidx & 2) ? dlt : 0;
    float ax = 0.f, ay = 0.f;
#pragma unroll
    for (int t0 = 0; t0 < 48; t0 += 4) {
      const float4 pm4 = *(const float4*)&pm_s[qidx][t0];
      const float pmv[4] = {pm4.x, pm4.y, pm4.z, pm4.w};
#pragma unroll
      for (int jj = 0; jj < 4; ++jj) {
        const int t = t0 + jj;
        const uint32_t vv = v_s[((t / 7) * 8 + (t % 7) + dl) * 64 + l];
        const float2 f = __half22float2(*(const __half2*)&vv);
        ax += pmv[jj] * f.x;
        ay += pmv[jj] * f.y;
      }
    }
    {
      const float pm48 = pm_s[qidx][48];
      const uint32_t vv = v_s[(6 * 8 + 6 + dl) * 64 + l];
      const float2 f = __half22float2(*(const __half2*)&vv);
      ax += pm48 * f.x;
      ay += pm48 * f.y;
    }
    const int posq = (2 * a + (qidx >> 2)) * WQ + 4 * b + (qidx & 3);
    out[(size_t)(2 * l + 0) * NPOS_Q + posq] = ax;
    out[(size_t)(2 * l + 1) * NPOS_Q + posq] = ay;
  }
}

// ---------------------------------------------------------------------------
extern "C" void kernel_launch(void* const* d_in, const int* in_sizes, int n_in,
                              void* d_out, int out_size, void* d_ws, size_t ws_size,
                              hipStream_t stream) {
  const float* q   = (const float*)d_in[0];
  const float* k   = (const float*)d_in[1];
  const float* v   = (const float*)d_in[2];
  const float* w_q = (const float*)d_in[3];
  const float* b_q = (const float*)d_in[4];
  const float* w_k = (const float*)d_in[5];
  const float* b_k = (const float*)d_in[6];
  float* out = (float*)d_out;

  float* wtq = (float*)d_ws;                       // [256][256]
  float* wtk = wtq + 65536;                        // [256][256]
  __half* qt_h = (__half*)(wtk + 65536);           // [9216][256]
  __half* kt_h = qt_h + (size_t)NPOS_Q * C_IN;     // [2304][256]
  __half* vt_h = kt_h + (size_t)NPOS_K * C_IN;     // [2304][128]

  prep<<<68, 256, 0, stream>>>(v, w_q, w_k, vt_h, wtq, wtk);
  proj_gemm<<<dim3(180, 4), 256, 0, stream>>>(q, k, wtq, wtk, b_q, b_k, qt_h, kt_h);
  natten_attn<<<dim3(HQ / 2, WQ / 4), 256, 0, stream>>>(qt_h, kt_h, vt_h, out);
}

// Round 10
// 51.855 us; speedup vs baseline: 2.3066x; 1.0970x over previous
//
#include <hip/hip_runtime.h>
#include <hip/hip_fp16.h>
#include <stdint.h>

// ---------------------------------------------------------------------------
// NATTEN cross attention, MI355X round 10.
// Window identity: key/value tap for query (x,y) =
//   (clip(x/2-3,0,41)+th, clip(y/2-3,0,41)+tw) in the native 48x48 grid.
// v10:
//  * attn: 512-thread blocks, ONE query per wave (was 2 serial) -> 24 waves/CU
//    (6/SIMD, 2x r9) hides the softmax shfl/exp dependency chains. Same 2x4
//    tile, same LDS layouts/staging as r9.
//  * proj: f16 dot2 core. prep packs w as half2 pairs wth[c2][o]; proj packs
//    staged f32 x pairs via v_cvt_pkrtz and runs 16 v_dot2_f32_f16 per c-pair:
//    VALU core halves, scalar w-load bytes halve (SGPR prefetch pressure).
//    f32 accumulate + f32 bias.
// ---------------------------------------------------------------------------

#define C_IN   256
#define C_V    128
#define HQ     96
#define WQ     96
#define HK     48
#define WK     48
#define NPOS_Q (HQ*WQ)    // 9216
#define NPOS_K (HK*WK)    // 2304
#define NH     8
#define DH     32
#define KS     7
#define K2     49

// async global->LDS DMA, 16 B/lane, lane l lands at lds_base + 16*l
#define GLD(gp, lp) __builtin_amdgcn_global_load_lds(                      \
    (const __attribute__((address_space(1))) void*)(uintptr_t)(gp),        \
    (__attribute__((address_space(3))) void*)(uintptr_t)(lp), 16, 0, 0)

typedef _Float16 h2_t __attribute__((ext_vector_type(2)));

static __device__ __forceinline__ float dot2f(uint32_t a, uint32_t b, float c) {
#if __has_builtin(__builtin_amdgcn_fdot2)
  h2_t ha = __builtin_bit_cast(h2_t, a);
  h2_t hb = __builtin_bit_cast(h2_t, b);
  return __builtin_amdgcn_fdot2(ha, hb, c, false);
#else
  const __half2 ha = *reinterpret_cast<const __half2*>(&a);
  const __half2 hb = *reinterpret_cast<const __half2*>(&b);
  const float2 fa = __half22float2(ha);
  const float2 fb = __half22float2(hb);
  return c + fa.x * fb.x + fa.y * fb.y;
#endif
}

static __device__ __forceinline__ uint32_t pkrtz(float a, float b) {
#if __has_builtin(__builtin_amdgcn_cvt_pkrtz)
  return __builtin_bit_cast(uint32_t, __builtin_amdgcn_cvt_pkrtz(a, b));
#else
  __half2 hv = __floats2half2_rn(a, b);
  return *reinterpret_cast<uint32_t*>(&hv);
#endif
}

// ---- prep -------------------------------------------------------------------
// blocks 0..35:  vt_h[pos][c] = (half)v[c][pos]    (64 pos each)
// blocks 36..67: wth[c2][o]   = pack(w[o][2c2], w[o][2c2+1])  (64x64 tiles)
__global__ __launch_bounds__(256) void prep(
    const float* __restrict__ v, const float* __restrict__ wq,
    const float* __restrict__ wk, __half* __restrict__ vt,
    uint32_t* __restrict__ wtqh, uint32_t* __restrict__ wtkh) {
  __shared__ float tile[128 * 65];
  const int bid = blockIdx.x;
  const int u = threadIdx.x;
  if (bid < 36) {
    const int p0 = bid * 64;
    for (int i = u; i < 128 * 64; i += 256) {
      int c = i >> 6, p = i & 63;
      tile[c * 65 + p] = v[(size_t)c * NPOS_K + p0 + p];
    }
    __syncthreads();
    uint32_t* vo = (uint32_t*)vt;
    for (int i = u; i < 64 * 64; i += 256) {
      int p = i >> 6, c2 = (i & 63) * 2;
      vo[(size_t)(p0 + p) * 64 + (i & 63)] =
          pkrtz(tile[c2 * 65 + p], tile[(c2 + 1) * 65 + p]);
    }
  } else {
    const int wb = bid - 36;
    const float* src = (wb < 16) ? wq : wk;
    uint32_t* dst = (wb < 16) ? wtqh : wtkh;
    const int ti = wb & 15;
    const int r0 = (ti >> 2) * 64, c0 = (ti & 3) * 64;   // o-range, c-range
    for (int i = u; i < 64 * 64; i += 256) {
      int ol = i >> 6, cl = i & 63;
      tile[cl * 65 + ol] = src[(size_t)(r0 + ol) * C_IN + c0 + cl];
    }
    __syncthreads();
    for (int i = u; i < 32 * 64; i += 256) {
      int cl2 = i >> 6, ol = i & 63;
      dst[(size_t)(c0 / 2 + cl2) * C_IN + r0 + ol] =
          pkrtz(tile[(2 * cl2) * 65 + ol], tile[(2 * cl2 + 1) * 65 + ol]);
    }
  }
}

// ---- SGPR-broadcast f16-dot2 projection -------------------------------------
// out_h[pos][o] = (half)(b[o] + sum_c2 dot2(w2[c2][o], x2[c2][pos]))
// block 256 thr = 4 waves; lane = pos; wave o-tile 16. grid (180, 4).
__global__ __launch_bounds__(256) void proj_gemm(
    const float* __restrict__ xq, const float* __restrict__ xk,
    const uint32_t* __restrict__ wtqh, const uint32_t* __restrict__ wtkh,
    const float* __restrict__ bq, const float* __restrict__ bk,
    __half* __restrict__ qo, __half* __restrict__ ko) {
  __shared__ float xs[2][64][64];

  const int mb = blockIdx.x;
  const float* x; const uint32_t* wt; const float* bias; __half* outp;
  int npos, m0;
  if (mb < 144) { x = xq; wt = wtqh; bias = bq; outp = qo; npos = NPOS_Q; m0 = mb * 64; }
  else          { x = xk; wt = wtkh; bias = bk; outp = ko; npos = NPOS_K; m0 = (mb - 144) * 64; }

  const int u   = threadIdx.x;
  const int l   = u & 63;
  const int wid = __builtin_amdgcn_readfirstlane(u >> 6);
  const int o0  = blockIdx.y * 64 + wid * 16;

  float acc[16];
#pragma unroll
  for (int j = 0; j < 16; ++j) acc[j] = 0.f;

#define STAGE(c0_, p_)                                                        \
  for (int g = wid; g < 16; g += 4)                                           \
    GLD(x + (size_t)((c0_) + g * 4 + (l >> 4)) * npos + m0 + (l & 15) * 4,    \
        &xs[p_][g * 4][0])

  STAGE(0, 0);
  __syncthreads();

  for (int ch = 0; ch < 4; ++ch) {
    const int cur = ch & 1;
    if (ch < 3) STAGE((ch + 1) * 64, cur ^ 1);
    const uint32_t* wbase = wt + (size_t)(ch * 32) * C_IN + o0;
#pragma unroll 4
    for (int kk2 = 0; kk2 < 32; ++kk2) {
      const uint32_t xp = pkrtz(xs[cur][2 * kk2][l], xs[cur][2 * kk2 + 1][l]);
      const uint4* w4 = (const uint4*)(wbase + (size_t)kk2 * C_IN);
      const uint4 w0 = w4[0], w1 = w4[1], w2 = w4[2], w3 = w4[3];
      acc[0]  = dot2f(w0.x, xp, acc[0]);  acc[1]  = dot2f(w0.y, xp, acc[1]);
      acc[2]  = dot2f(w0.z, xp, acc[2]);  acc[3]  = dot2f(w0.w, xp, acc[3]);
      acc[4]  = dot2f(w1.x, xp, acc[4]);  acc[5]  = dot2f(w1.y, xp, acc[5]);
      acc[6]  = dot2f(w1.z, xp, acc[6]);  acc[7]  = dot2f(w1.w, xp, acc[7]);
      acc[8]  = dot2f(w2.x, xp, acc[8]);  acc[9]  = dot2f(w2.y, xp, acc[9]);
      acc[10] = dot2f(w2.z, xp, acc[10]); acc[11] = dot2f(w2.w, xp, acc[11]);
      acc[12] = dot2f(w3.x, xp, acc[12]); acc[13] = dot2f(w3.y, xp, acc[13]);
      acc[14] = dot2f(w3.z, xp, acc[14]); acc[15] = dot2f(w3.w, xp, acc[15]);
    }
    __syncthreads();
  }
#undef STAGE

  const float4 b0 = *(const float4*)&bias[o0];
  const float4 b1 = *(const float4*)&bias[o0 + 4];
  const float4 b2 = *(const float4*)&bias[o0 + 8];
  const float4 b3 = *(const float4*)&bias[o0 + 12];
  const float bb[16] = {b0.x, b0.y, b0.z, b0.w, b1.x, b1.y, b1.z, b1.w,
                        b2.x, b2.y, b2.z, b2.w, b3.x, b3.y, b3.z, b3.w};
  uint32_t pk[8];
#pragma unroll
  for (int j = 0; j < 8; ++j) {
    __half2 hv = __floats2half2_rn(acc[2 * j] + bb[2 * j], acc[2 * j + 1] + bb[2 * j + 1]);
    pk[j] = *reinterpret_cast<uint32_t*>(&hv);
  }
  uint32_t* op = (uint32_t*)(outp + (size_t)(m0 + l) * C_IN + o0);
  uint4 s0 = {pk[0], pk[1], pk[2], pk[3]};
  uint4 s1 = {pk[4], pk[5], pk[6], pk[7]};
  *(uint4*)op = s0;
  *(uint4*)(op + 4) = s1;
}

// ---- fused neighborhood attention: 2x4 tile, 8 waves, 1 query/wave ---------
// k LDS: [7 rows][8 cols][512B], within-tap slot s holds source chunk
//   (s&7)*4+(s>>3) -> read (h,j2) at slot j2*8+h -> granule class = h.
// v LDS: 56 taps x 256B linear. Wave w (0..7) owns query qidx=w.
__global__ __launch_bounds__(512, 6) void natten_attn(
    const __half* __restrict__ qt, const __half* __restrict__ kt,
    const __half* __restrict__ vt, float* __restrict__ out) {
  __shared__ uint32_t k_s[7168];            // 28672 B
  __shared__ uint32_t v_s[3584];            // 14336 B
  __shared__ float pm_s[8][52];             //  1664 B

  const int u  = threadIdx.x;
  const int a  = blockIdx.x;               // 0..47 : x-pair 2a..2a+1
  const int b  = blockIdx.y;               // 0..23 : y-quad 4b..4b+3
  const int sh  = min(max(a - 3, 0), HK - KS);
  const int sw0 = min(max(2 * b - 3, 0), WK - KS);
  const int sw1 = min(max(2 * b - 2, 0), WK - KS);
  const int dlt = sw1 - sw0;               // 0 or 1

  const int l = u & 63;
  const int w = __builtin_amdgcn_readfirstlane(u >> 6);  // wave = query
  const int h = l >> 3;
  const int r = l & 7;

  // ---- k DMA: 28 instrs over 8 waves
  for (int idx = w; idx < 28; idx += 8) {
    const int th = idx >> 2, pr = idx & 3;
    const int col = min(sw0 + pr * 2 + (l >> 5), WK - 1);
    const int slot = l & 31;
    const int csrc = (slot & 7) * 4 + (slot >> 3);
    GLD(kt + (size_t)((sh + th) * WK + col) * C_IN + csrc * 8,
        (char*)k_s + th * 4096 + pr * 1024);
  }
  // ---- v DMA: 14 instrs over 8 waves, linear
  for (int idx = w; idx < 14; idx += 8) {
    const int j = idx * 4 + (l >> 4);      // region tap 0..55 = th*8+cc
    const int col = min(sw0 + (j & 7), WK - 1);
    GLD(vt + (size_t)((sh + (j >> 3)) * WK + col) * C_V + (l & 15) * 8,
        (char*)v_s + idx * 1024);
  }
  // ---- q slice for this wave's query ---------------------------------------
  const int qx = 2 * a + (w >> 2);
  const int qy = 4 * b + (w & 3);
  const int dl = (w & 2) ? dlt : 0;
  const uint4* qp = (const uint4*)(qt + (size_t)(qx * WQ + qy) * C_IN + h * DH);
  const uint4 qa = qp[0], qb = qp[1], qc = qp[2], qd = qp[3];
  const uint32_t q16[16] = {qa.x, qa.y, qa.z, qa.w, qb.x, qb.y, qb.z, qb.w,
                            qc.x, qc.y, qc.z, qc.w, qd.x, qd.y, qd.z, qd.w};

  __syncthreads();                         // ONLY barrier: all DMA drained

  const float scale = 0.17677669529663687f;  // 32^-0.5

  // ---- logits: taps t = r + 8i ----------------------------------------------
  int th = (r == 7) ? 1 : 0;
  int tw = (r == 7) ? 0 : r;
  float sreg[7];
#pragma unroll
  for (int i = 0; i < 7; ++i) {
    const int t = r + 8 * i;
    const uint32_t* krow = k_s + (th * 8 + tw + dl) * 128 + h * 4;
    float s = 0.f;
#pragma unroll
    for (int j2 = 0; j2 < 4; ++j2) {
      const uint4 kv = *(const uint4*)(krow + j2 * 32);
      s = dot2f(kv.x, q16[j2 * 4 + 0], s);
      s = dot2f(kv.y, q16[j2 * 4 + 1], s);
      s = dot2f(kv.z, q16[j2 * 4 + 2], s);
      s = dot2f(kv.w, q16[j2 * 4 + 3], s);
    }
    sreg[i] = (t < K2) ? s * scale : -1e30f;
    tw += 1; th += 1;
    if (tw >= 7) { tw -= 7; th += 1; }     // advance tap by 8 in base-7
  }

  // ---- softmax per (query,head): reduce over r = lane bits 0..2 -------------
  float m = sreg[0];
#pragma unroll
  for (int i = 1; i < 7; ++i) m = fmaxf(m, sreg[i]);
  m = fmaxf(m, __shfl_xor(m, 1));
  m = fmaxf(m, __shfl_xor(m, 2));
  m = fmaxf(m, __shfl_xor(m, 4));
  float e[7];
  float sl = 0.f;
#pragma unroll
  for (int i = 0; i < 7; ++i) { e[i] = __expf(sreg[i] - m); sl += e[i]; }
  sl += __shfl_xor(sl, 1);
  sl += __shfl_xor(sl, 2);
  sl += __shfl_xor(sl, 4);
  const float rinv = 1.f / (8.f * sl);

  // ---- head-mean over h = lane bits 3..5; lanes h==0 write pm (wave-private)
#pragma unroll
  for (int i = 0; i < 7; ++i) {
    float pv = e[i] * rinv;
    pv += __shfl_xor(pv, 8);
    pv += __shfl_xor(pv, 16);
    pv += __shfl_xor(pv, 32);
    const int t = r + 8 * i;
    if (h == 0 && t < K2) pm_s[w][t] = pv;
  }
  if (l == 0) { pm_s[w][49] = 0.f; pm_s[w][50] = 0.f; pm_s[w][51] = 0.f; }

  // ---- PV: lane = 2-channel slot --------------------------------------------
  float ax = 0.f, ay = 0.f;
#pragma unroll
  for (int t0 = 0; t0 < 48; t0 += 4) {
    const float4 pm4 = *(const float4*)&pm_s[w][t0];
    const float pmv[4] = {pm4.x, pm4.y, pm4.z, pm4.w};
#pragma unroll
    for (int jj = 0; jj < 4; ++jj) {
      const int t = t0 + jj;
      const uint32_t vv = v_s[((t / 7) * 8 + (t % 7) + dl) * 64 + l];
      const float2 f = __half22float2(*(const __half2*)&vv);
      ax += pmv[jj] * f.x;
      ay += pmv[jj] * f.y;
    }
  }
  {
    const float pm48 = pm_s[w][48];
    const uint32_t vv = v_s[(6 * 8 + 6 + dl) * 64 + l];
    const float2 f = __half22float2(*(const __half2*)&vv);
    ax += pm48 * f.x;
    ay += pm48 * f.y;
  }
  const int posq = qx * WQ + qy;
  out[(size_t)(2 * l + 0) * NPOS_Q + posq] = ax;
  out[(size_t)(2 * l + 1) * NPOS_Q + posq] = ay;
}

// ---------------------------------------------------------------------------
extern "C" void kernel_launch(void* const* d_in, const int* in_sizes, int n_in,
                              void* d_out, int out_size, void* d_ws, size_t ws_size,
                              hipStream_t stream) {
  const float* q   = (const float*)d_in[0];
  const float* k   = (const float*)d_in[1];
  const float* v   = (const float*)d_in[2];
  const float* w_q = (const float*)d_in[3];
  const float* b_q = (const float*)d_in[4];
  const float* w_k = (const float*)d_in[5];
  const float* b_k = (const float*)d_in[6];
  float* out = (float*)d_out;

  uint32_t* wtqh = (uint32_t*)d_ws;                 // [128][256] packed half2
  uint32_t* wtkh = wtqh + 32768;                    // [128][256]
  __half* qt_h = (__half*)(wtkh + 32768);           // [9216][256]
  __half* kt_h = qt_h + (size_t)NPOS_Q * C_IN;      // [2304][256]
  __half* vt_h = kt_h + (size_t)NPOS_K * C_IN;      // [2304][128]

  prep<<<68, 256, 0, stream>>>(v, w_q, w_k, vt_h, wtqh, wtkh);
  proj_gemm<<<dim3(180, 4), 256, 0, stream>>>(q, k, wtqh, wtkh, b_q, b_k, qt_h, kt_h);
  natten_attn<<<dim3(HQ / 2, WQ / 4), 512, 0, stream>>>(qt_h, kt_h, vt_h, out);
}

// Round 11
// 47.922 us; speedup vs baseline: 2.4959x; 1.0821x over previous
//
#include <hip/hip_runtime.h>
#include <hip/hip_fp16.h>
#include <stdint.h>

// ---------------------------------------------------------------------------
// NATTEN cross attention, MI355X round 11.
// Window identity: key/value tap for query (x,y) =
//   (clip(x/2-3,0,41)+th, clip(y/2-3,0,41)+tw) in the native 48x48 grid.
// v11:
//  * proj -> MFMA (v_mfma_f32_16x16x32_f16). Wave = 16pos x 64o strip,
//    8 K-steps x (5 b128 frag loads + 4 MFMA), f32 acc, no LDS, no barriers.
//    Fragment maps: A[m][k]: m=l&15, k=(l>>4)*8+j (xt[pos][c], c-contig);
//    B[k][n]: n=l&15, k=(l>>4)*8+j (w[o][c], c-contig, NO transpose needed);
//    C/D: col=l&15, row=(l>>4)*4+reg (guide-verified, m89).
//  * prep expanded: q,k -> pos-major f16 xt (A operand), w -> f16 (B operand),
//    v transpose+cvt, all in one 412-block launch.
//  * attn: bit-identical to r10 (512 thr, 1 query/wave, 2x4 tile).
// ---------------------------------------------------------------------------

#define C_IN   256
#define C_V    128
#define HQ     96
#define WQ     96
#define HK     48
#define WK     48
#define NPOS_Q (HQ*WQ)    // 9216
#define NPOS_K (HK*WK)    // 2304
#define NH     8
#define DH     32
#define KS     7
#define K2     49

// async global->LDS DMA, 16 B/lane, lane l lands at lds_base + 16*l
#define GLD(gp, lp) __builtin_amdgcn_global_load_lds(                      \
    (const __attribute__((address_space(1))) void*)(uintptr_t)(gp),        \
    (__attribute__((address_space(3))) void*)(uintptr_t)(lp), 16, 0, 0)

typedef _Float16 f16x8 __attribute__((ext_vector_type(8)));
typedef float f32x4 __attribute__((ext_vector_type(4)));

static __device__ __forceinline__ float dot2f(uint32_t a, uint32_t b, float c) {
#if __has_builtin(__builtin_amdgcn_fdot2)
  typedef _Float16 h2_t __attribute__((ext_vector_type(2)));
  h2_t ha = __builtin_bit_cast(h2_t, a);
  h2_t hb = __builtin_bit_cast(h2_t, b);
  return __builtin_amdgcn_fdot2(ha, hb, c, false);
#else
  const __half2 ha = *reinterpret_cast<const __half2*>(&a);
  const __half2 hb = *reinterpret_cast<const __half2*>(&b);
  const float2 fa = __half22float2(ha);
  const float2 fb = __half22float2(hb);
  return c + fa.x * fb.x + fa.y * fb.y;
#endif
}

static __device__ __forceinline__ uint32_t pkrtz(float a, float b) {
#if __has_builtin(__builtin_amdgcn_cvt_pkrtz)
  return __builtin_bit_cast(uint32_t, __builtin_amdgcn_cvt_pkrtz(a, b));
#else
  __half2 hv = __floats2half2_rn(a, b);
  return *reinterpret_cast<uint32_t*>(&hv);
#endif
}

// ---- prep -------------------------------------------------------------------
// bid 0..287  : q -> xtq[pos][c] f16   (144 pos-tiles x 2 c-halves)
// bid 288..359: k -> xtk[pos][c] f16   (36 x 2)
// bid 360..395: v -> vt[pos][c] f16    (36 pos-tiles)
// bid 396..411: w_q, w_k -> f16 (layout unchanged [o][c])
__global__ __launch_bounds__(256) void prep(
    const float* __restrict__ q, const float* __restrict__ k,
    const float* __restrict__ v, const float* __restrict__ wq,
    const float* __restrict__ wk, uint32_t* __restrict__ xtq,
    uint32_t* __restrict__ xtk, uint32_t* __restrict__ vt,
    uint32_t* __restrict__ wqh, uint32_t* __restrict__ wkh) {
  __shared__ float tile[128 * 65];
  const int bid = blockIdx.x;
  const int u = threadIdx.x;

  if (bid < 360) {                     // q or k transpose+cvt
    const float* src; uint32_t* dst; int npos, tb;
    if (bid < 288) { src = q; dst = xtq; npos = NPOS_Q; tb = bid; }
    else           { src = k; dst = xtk; npos = NPOS_K; tb = bid - 288; }
    const int p0 = (tb >> 1) * 64;
    const int c0 = (tb & 1) * 128;
    for (int i = u; i < 128 * 64; i += 256) {
      int c = i >> 6, p = i & 63;
      tile[c * 65 + p] = src[(size_t)(c0 + c) * npos + p0 + p];
    }
    __syncthreads();
    for (int i = u; i < 64 * 64; i += 256) {
      int p = i >> 6, c2 = i & 63;
      dst[(size_t)(p0 + p) * 128 + (c0 >> 1) + c2] =
          pkrtz(tile[(2 * c2) * 65 + p], tile[(2 * c2 + 1) * 65 + p]);
    }
  } else if (bid < 396) {              // v transpose+cvt
    const int p0 = (bid - 360) * 64;
    for (int i = u; i < 128 * 64; i += 256) {
      int c = i >> 6, p = i & 63;
      tile[c * 65 + p] = v[(size_t)c * NPOS_K + p0 + p];
    }
    __syncthreads();
    for (int i = u; i < 64 * 64; i += 256) {
      int p = i >> 6, c2 = i & 63;
      vt[(size_t)(p0 + p) * 64 + c2] =
          pkrtz(tile[(2 * c2) * 65 + p], tile[(2 * c2 + 1) * 65 + p]);
    }
  } else {                             // w cvt (no transpose)
    const int tid = (bid - 396) * 256 + u;
    const float2* q2 = (const float2*)wq;
    const float2* k2 = (const float2*)wk;
    for (int j = tid; j < 32768; j += 4096) {
      const float2 a = q2[j];
      wqh[j] = pkrtz(a.x, a.y);
      const float2 b2 = k2[j];
      wkh[j] = pkrtz(b2.x, b2.y);
    }
  }
}

// ---- MFMA projection --------------------------------------------------------
// out_h[pos][o] = (half)(b[o] + sum_c x[pos][c]*w[o][c]); f32 accumulate.
// grid (180, 4), 256 thr = 4 waves; wave = 16 pos x 64 o (4 acc tiles).
__global__ __launch_bounds__(256) void proj_mfma(
    const __half* __restrict__ xtq, const __half* __restrict__ xtk,
    const __half* __restrict__ wqh, const __half* __restrict__ wkh,
    const float* __restrict__ bq, const float* __restrict__ bk,
    __half* __restrict__ qo, __half* __restrict__ ko) {
  const int mb = blockIdx.x;
  const __half* xt; const __half* wh; const float* bias; __half* outp;
  int m0;
  if (mb < 144) { xt = xtq; wh = wqh; bias = bq; outp = qo; m0 = mb * 64; }
  else          { xt = xtk; wh = wkh; bias = bk; outp = ko; m0 = (mb - 144) * 64; }
  const int n0 = blockIdx.y * 64;

  const int u  = threadIdx.x;
  const int l  = u & 63;
  const int wv = u >> 6;           // wave: rows m0+wv*16 .. +15
  const int lr = l & 15;           // A-row / B-col / D-col
  const int lk = l >> 4;           // k-chunk 0..3 / D-row group

  f32x4 acc[4];
#pragma unroll
  for (int nt = 0; nt < 4; ++nt) acc[nt] = (f32x4){0.f, 0.f, 0.f, 0.f};

  const __half* aptr = xt + (size_t)(m0 + wv * 16 + lr) * C_IN + lk * 8;
#pragma unroll
  for (int ks = 0; ks < 8; ++ks) {
    const f16x8 a = *(const f16x8*)(aptr + ks * 32);
#pragma unroll
    for (int nt = 0; nt < 4; ++nt) {
      const f16x8 b = *(const f16x8*)(wh + (size_t)(n0 + nt * 16 + lr) * C_IN +
                                      ks * 32 + lk * 8);
      acc[nt] = __builtin_amdgcn_mfma_f32_16x16x32_f16(a, b, acc[nt], 0, 0, 0);
    }
  }

#pragma unroll
  for (int nt = 0; nt < 4; ++nt) {
    const int o = n0 + nt * 16 + lr;
    const float bv = bias[o];
#pragma unroll
    for (int r = 0; r < 4; ++r) {
      const int pos = m0 + wv * 16 + lk * 4 + r;
      outp[(size_t)pos * C_IN + o] = __float2half(acc[nt][r] + bv);
    }
  }
}

// ---- fused neighborhood attention (identical to r10) -----------------------
__global__ __launch_bounds__(512, 6) void natten_attn(
    const __half* __restrict__ qt, const __half* __restrict__ kt,
    const __half* __restrict__ vt, float* __restrict__ out) {
  __shared__ uint32_t k_s[7168];            // 28672 B
  __shared__ uint32_t v_s[3584];            // 14336 B
  __shared__ float pm_s[8][52];             //  1664 B

  const int u  = threadIdx.x;
  const int a  = blockIdx.x;               // 0..47 : x-pair 2a..2a+1
  const int b  = blockIdx.y;               // 0..23 : y-quad 4b..4b+3
  const int sh  = min(max(a - 3, 0), HK - KS);
  const int sw0 = min(max(2 * b - 3, 0), WK - KS);
  const int sw1 = min(max(2 * b - 2, 0), WK - KS);
  const int dlt = sw1 - sw0;               // 0 or 1

  const int l = u & 63;
  const int w = __builtin_amdgcn_readfirstlane(u >> 6);  // wave = query
  const int h = l >> 3;
  const int r = l & 7;

  for (int idx = w; idx < 28; idx += 8) {
    const int th = idx >> 2, pr = idx & 3;
    const int col = min(sw0 + pr * 2 + (l >> 5), WK - 1);
    const int slot = l & 31;
    const int csrc = (slot & 7) * 4 + (slot >> 3);
    GLD(kt + (size_t)((sh + th) * WK + col) * C_IN + csrc * 8,
        (char*)k_s + th * 4096 + pr * 1024);
  }
  for (int idx = w; idx < 14; idx += 8) {
    const int j = idx * 4 + (l >> 4);      // region tap 0..55 = th*8+cc
    const int col = min(sw0 + (j & 7), WK - 1);
    GLD(vt + (size_t)((sh + (j >> 3)) * WK + col) * C_V + (l & 15) * 8,
        (char*)v_s + idx * 1024);
  }
  const int qx = 2 * a + (w >> 2);
  const int qy = 4 * b + (w & 3);
  const int dl = (w & 2) ? dlt : 0;
  const uint4* qp = (const uint4*)(qt + (size_t)(qx * WQ + qy) * C_IN + h * DH);
  const uint4 qa = qp[0], qb = qp[1], qc = qp[2], qd = qp[3];
  const uint32_t q16[16] = {qa.x, qa.y, qa.z, qa.w, qb.x, qb.y, qb.z, qb.w,
                            qc.x, qc.y, qc.z, qc.w, qd.x, qd.y, qd.z, qd.w};

  __syncthreads();                         // ONLY barrier: all DMA drained

  const float scale = 0.17677669529663687f;  // 32^-0.5

  int th = (r == 7) ? 1 : 0;
  int tw = (r == 7) ? 0 : r;
  float sreg[7];
#pragma unroll
  for (int i = 0; i < 7; ++i) {
    const int t = r + 8 * i;
    const uint32_t* krow = k_s + (th * 8 + tw + dl) * 128 + h * 4;
    float s = 0.f;
#pragma unroll
    for (int j2 = 0; j2 < 4; ++j2) {
      const uint4 kv = *(const uint4*)(krow + j2 * 32);
      s = dot2f(kv.x, q16[j2 * 4 + 0], s);
      s = dot2f(kv.y, q16[j2 * 4 + 1], s);
      s = dot2f(kv.z, q16[j2 * 4 + 2], s);
      s = dot2f(kv.w, q16[j2 * 4 + 3], s);
    }
    sreg[i] = (t < K2) ? s * scale : -1e30f;
    tw += 1; th += 1;
    if (tw >= 7) { tw -= 7; th += 1; }     // advance tap by 8 in base-7
  }

  float m = sreg[0];
#pragma unroll
  for (int i = 1; i < 7; ++i) m = fmaxf(m, sreg[i]);
  m = fmaxf(m, __shfl_xor(m, 1));
  m = fmaxf(m, __shfl_xor(m, 2));
  m = fmaxf(m, __shfl_xor(m, 4));
  float e[7];
  float sl = 0.f;
#pragma unroll
  for (int i = 0; i < 7; ++i) { e[i] = __expf(sreg[i] - m); sl += e[i]; }
  sl += __shfl_xor(sl, 1);
  sl += __shfl_xor(sl, 2);
  sl += __shfl_xor(sl, 4);
  const float rinv = 1.f / (8.f * sl);

#pragma unroll
  for (int i = 0; i < 7; ++i) {
    float pv = e[i] * rinv;
    pv += __shfl_xor(pv, 8);
    pv += __shfl_xor(pv, 16);
    pv += __shfl_xor(pv, 32);
    const int t = r + 8 * i;
    if (h == 0 && t < K2) pm_s[w][t] = pv;
  }
  if (l == 0) { pm_s[w][49] = 0.f; pm_s[w][50] = 0.f; pm_s[w][51] = 0.f; }

  float ax = 0.f, ay = 0.f;
#pragma unroll
  for (int t0 = 0; t0 < 48; t0 += 4) {
    const float4 pm4 = *(const float4*)&pm_s[w][t0];
    const float pmv[4] = {pm4.x, pm4.y, pm4.z, pm4.w};
#pragma unroll
    for (int jj = 0; jj < 4; ++jj) {
      const int t = t0 + jj;
      const uint32_t vv = v_s[((t / 7) * 8 + (t % 7) + dl) * 64 + l];
      const float2 f = __half22float2(*(const __half2*)&vv);
      ax += pmv[jj] * f.x;
      ay += pmv[jj] * f.y;
    }
  }
  {
    const float pm48 = pm_s[w][48];
    const uint32_t vv = v_s[(6 * 8 + 6 + dl) * 64 + l];
    const float2 f = __half22float2(*(const __half2*)&vv);
    ax += pm48 * f.x;
    ay += pm48 * f.y;
  }
  const int posq = qx * WQ + qy;
  out[(size_t)(2 * l + 0) * NPOS_Q + posq] = ax;
  out[(size_t)(2 * l + 1) * NPOS_Q + posq] = ay;
}

// ---------------------------------------------------------------------------
extern "C" void kernel_launch(void* const* d_in, const int* in_sizes, int n_in,
                              void* d_out, int out_size, void* d_ws, size_t ws_size,
                              hipStream_t stream) {
  const float* q   = (const float*)d_in[0];
  const float* k   = (const float*)d_in[1];
  const float* v   = (const float*)d_in[2];
  const float* w_q = (const float*)d_in[3];
  const float* b_q = (const float*)d_in[4];
  const float* w_k = (const float*)d_in[5];
  const float* b_k = (const float*)d_in[6];
  float* out = (float*)d_out;

  __half* xtq = (__half*)d_ws;                     // [9216][256] f16 (x^T)
  __half* xtk = xtq + (size_t)NPOS_Q * C_IN;       // [2304][256]
  __half* vt  = xtk + (size_t)NPOS_K * C_IN;       // [2304][128]
  __half* wqh = vt + (size_t)NPOS_K * C_V;         // [256][256] f16
  __half* wkh = wqh + 65536;                       // [256][256]
  __half* qt  = wkh + 65536;                       // [9216][256] f16
  __half* kt  = qt + (size_t)NPOS_Q * C_IN;        // [2304][256]

  prep<<<412, 256, 0, stream>>>(q, k, v, w_q, w_k,
                                (uint32_t*)xtq, (uint32_t*)xtk, (uint32_t*)vt,
                                (uint32_t*)wqh, (uint32_t*)wkh);
  proj_mfma<<<dim3(180, 4), 256, 0, stream>>>(xtq, xtk, wqh, wkh, b_q, b_k, qt, kt);
  natten_attn<<<dim3(HQ / 2, WQ / 4), 512, 0, stream>>>(qt, kt, vt, out);
}

// Round 12
// 44.133 us; speedup vs baseline: 2.7102x; 1.0859x over previous
//
#include <hip/hip_runtime.h>
#include <hip/hip_fp16.h>
#include <stdint.h>

// ---------------------------------------------------------------------------
// NATTEN cross attention, MI355X round 12.
// Window identity: key/value tap for query (x,y) =
//   (clip(x/2-3,0,41)+th, clip(y/2-3,0,41)+tw) in the native 48x48 grid.
// v12 (attn only; prep/proj bit-identical to r11):
//   logits via MFMA. Wave = head h: A = Q[16rows(8q dup)][k=32c of head h]
//   (1 global b128/lane), B = K[56+8pad taps][32c] from k_s LDS (4 b128,
//   source-swizzled slot^((tap&1)<<2) for uniform bank-quad spread),
//   4x mfma_f32_16x16x32_f16 -> logits[8q][64 region taps] in 16 f32/lane.
//   Mask per (q,tap) (window-col + tap<56) -> -1e30; softmax over 16 tap-
//   lanes x 4 tiles via shfl(1,2,4,8); p*(1/(8 sum)) packed f16 -> p_s
//   [h][rt][q] (8KB); 256-thr cross-wave head-sum -> pm_s[q][rt] f32;
//   PV unchanged VALU (wave=query, 56 region taps, pm=0 at invalid).
//   LDS 53.2KB (3 blocks/CU), 3 barriers.
// ---------------------------------------------------------------------------

#define C_IN   256
#define C_V    128
#define HQ     96
#define WQ     96
#define HK     48
#define WK     48
#define NPOS_Q (HQ*WQ)    // 9216
#define NPOS_K (HK*WK)    // 2304
#define NH     8
#define DH     32
#define KS     7
#define K2     49

// async global->LDS DMA, 16 B/lane, lane l lands at lds_base + 16*l
#define GLD(gp, lp) __builtin_amdgcn_global_load_lds(                      \
    (const __attribute__((address_space(1))) void*)(uintptr_t)(gp),        \
    (__attribute__((address_space(3))) void*)(uintptr_t)(lp), 16, 0, 0)

typedef _Float16 f16x8 __attribute__((ext_vector_type(8)));
typedef float f32x4 __attribute__((ext_vector_type(4)));

static __device__ __forceinline__ uint32_t pkrtz(float a, float b) {
#if __has_builtin(__builtin_amdgcn_cvt_pkrtz)
  return __builtin_bit_cast(uint32_t, __builtin_amdgcn_cvt_pkrtz(a, b));
#else
  __half2 hv = __floats2half2_rn(a, b);
  return *reinterpret_cast<uint32_t*>(&hv);
#endif
}

// ---- prep (identical to r11) ------------------------------------------------
__global__ __launch_bounds__(256) void prep(
    const float* __restrict__ q, const float* __restrict__ k,
    const float* __restrict__ v, const float* __restrict__ wq,
    const float* __restrict__ wk, uint32_t* __restrict__ xtq,
    uint32_t* __restrict__ xtk, uint32_t* __restrict__ vt,
    uint32_t* __restrict__ wqh, uint32_t* __restrict__ wkh) {
  __shared__ float tile[128 * 65];
  const int bid = blockIdx.x;
  const int u = threadIdx.x;

  if (bid < 360) {                     // q or k transpose+cvt
    const float* src; uint32_t* dst; int npos, tb;
    if (bid < 288) { src = q; dst = xtq; npos = NPOS_Q; tb = bid; }
    else           { src = k; dst = xtk; npos = NPOS_K; tb = bid - 288; }
    const int p0 = (tb >> 1) * 64;
    const int c0 = (tb & 1) * 128;
    for (int i = u; i < 128 * 64; i += 256) {
      int c = i >> 6, p = i & 63;
      tile[c * 65 + p] = src[(size_t)(c0 + c) * npos + p0 + p];
    }
    __syncthreads();
    for (int i = u; i < 64 * 64; i += 256) {
      int p = i >> 6, c2 = i & 63;
      dst[(size_t)(p0 + p) * 128 + (c0 >> 1) + c2] =
          pkrtz(tile[(2 * c2) * 65 + p], tile[(2 * c2 + 1) * 65 + p]);
    }
  } else if (bid < 396) {              // v transpose+cvt
    const int p0 = (bid - 360) * 64;
    for (int i = u; i < 128 * 64; i += 256) {
      int c = i >> 6, p = i & 63;
      tile[c * 65 + p] = v[(size_t)c * NPOS_K + p0 + p];
    }
    __syncthreads();
    for (int i = u; i < 64 * 64; i += 256) {
      int p = i >> 6, c2 = i & 63;
      vt[(size_t)(p0 + p) * 64 + c2] =
          pkrtz(tile[(2 * c2) * 65 + p], tile[(2 * c2 + 1) * 65 + p]);
    }
  } else {                             // w cvt (no transpose)
    const int tid = (bid - 396) * 256 + u;
    const float2* q2 = (const float2*)wq;
    const float2* k2 = (const float2*)wk;
    for (int j = tid; j < 32768; j += 4096) {
      const float2 a = q2[j];
      wqh[j] = pkrtz(a.x, a.y);
      const float2 b2 = k2[j];
      wkh[j] = pkrtz(b2.x, b2.y);
    }
  }
}

// ---- MFMA projection (identical to r11) -------------------------------------
__global__ __launch_bounds__(256) void proj_mfma(
    const __half* __restrict__ xtq, const __half* __restrict__ xtk,
    const __half* __restrict__ wqh, const __half* __restrict__ wkh,
    const float* __restrict__ bq, const float* __restrict__ bk,
    __half* __restrict__ qo, __half* __restrict__ ko) {
  const int mb = blockIdx.x;
  const __half* xt; const __half* wh; const float* bias; __half* outp;
  int m0;
  if (mb < 144) { xt = xtq; wh = wqh; bias = bq; outp = qo; m0 = mb * 64; }
  else          { xt = xtk; wh = wkh; bias = bk; outp = ko; m0 = (mb - 144) * 64; }
  const int n0 = blockIdx.y * 64;

  const int u  = threadIdx.x;
  const int l  = u & 63;
  const int wv = u >> 6;
  const int lr = l & 15;
  const int lk = l >> 4;

  f32x4 acc[4];
#pragma unroll
  for (int nt = 0; nt < 4; ++nt) acc[nt] = (f32x4){0.f, 0.f, 0.f, 0.f};

  const __half* aptr = xt + (size_t)(m0 + wv * 16 + lr) * C_IN + lk * 8;
#pragma unroll
  for (int ks = 0; ks < 8; ++ks) {
    const f16x8 a = *(const f16x8*)(aptr + ks * 32);
#pragma unroll
    for (int nt = 0; nt < 4; ++nt) {
      const f16x8 b = *(const f16x8*)(wh + (size_t)(n0 + nt * 16 + lr) * C_IN +
                                      ks * 32 + lk * 8);
      acc[nt] = __builtin_amdgcn_mfma_f32_16x16x32_f16(a, b, acc[nt], 0, 0, 0);
    }
  }

#pragma unroll
  for (int nt = 0; nt < 4; ++nt) {
    const int o = n0 + nt * 16 + lr;
    const float bv = bias[o];
#pragma unroll
    for (int r = 0; r < 4; ++r) {
      const int pos = m0 + wv * 16 + lk * 4 + r;
      outp[(size_t)pos * C_IN + o] = __float2half(acc[nt][r] + bv);
    }
  }
}

// ---- fused neighborhood attention: MFMA logits ------------------------------
// block = 512 thr = 8 waves = 8 heads; 2x4 query tile; region 7x8 = 56 taps.
// k_s: 56 taps x 512B, 16B slot s holds source chunk s^((t&1)<<2).
// v_s: 56 taps x 256B linear. p_s: [h][rt][q] f16. pm_s: [q][rt] f32.
__global__ __launch_bounds__(512, 6) void natten_attn(
    const __half* __restrict__ qt, const __half* __restrict__ kt,
    const __half* __restrict__ vt, float* __restrict__ out) {
  __shared__ uint32_t k_s[7168];            // 28672 B
  __shared__ uint32_t v_s[3584];            // 14336 B
  __shared__ uint32_t p_s[2048];            //  8192 B  [h][rt 0..63][q 0..7] f16
  __shared__ float pm_s[8][64];             //  2048 B

  const int u  = threadIdx.x;
  const int a  = blockIdx.x;               // 0..47 : x-pair 2a..2a+1
  const int b  = blockIdx.y;               // 0..23 : y-quad 4b..4b+3
  const int sh  = min(max(a - 3, 0), HK - KS);
  const int sw0 = min(max(2 * b - 3, 0), WK - KS);
  const int sw1 = min(max(2 * b - 2, 0), WK - KS);
  const int dlt = sw1 - sw0;               // 0 or 1

  const int l = u & 63;
  const int w = __builtin_amdgcn_readfirstlane(u >> 6);  // wave = head h
  const int lr = l & 15;
  const int lk = l >> 4;

  // ---- k DMA: 28 instrs; instr idx covers region taps 2idx, 2idx+1 ---------
  // LDS 16B-slot s of tap t holds source chunk g = s ^ ((t&1)<<2).
  for (int idx = w; idx < 28; idx += 8) {
    const int tap = 2 * idx + (l >> 5);
    const int s = l & 31;
    const int g = s ^ ((tap & 1) << 2);
    const int col = min(sw0 + (tap & 7), WK - 1);
    GLD(kt + (size_t)((sh + (tap >> 3)) * WK + col) * C_IN + g * 8,
        (char*)k_s + idx * 1024);
  }
  // ---- v DMA: 14 instrs; 4 region taps each, linear [tap][128c] ------------
  for (int idx = w; idx < 14; idx += 8) {
    const int tap = idx * 4 + (l >> 4);
    const int col = min(sw0 + (tap & 7), WK - 1);
    GLD(vt + (size_t)((sh + (tap >> 3)) * WK + col) * C_V + (l & 15) * 8,
        (char*)v_s + idx * 1024);
  }

  // ---- A-operand: Q rows (8 queries, rows 8-15 dup), head w ----------------
  const int qrow = lr & 7;
  const int aqx = 2 * a + (qrow >> 2);
  const int aqy = 4 * b + (qrow & 3);
  const f16x8 afrag = *(const f16x8*)(
      qt + (size_t)(aqx * WQ + aqy) * C_IN + w * DH + lk * 8);

  __syncthreads();                         // barrier 1: staging done

  // ---- logits MFMA: 4 tap-tiles --------------------------------------------
  f32x4 acc[4];
#pragma unroll
  for (int nt = 0; nt < 4; ++nt) {
    const int t = min(nt * 16 + lr, 55);
    const int byte = t * 512 + (((w * 4 + lk) ^ ((t & 1) << 2)) * 16);
    const f16x8 bfrag = *(const f16x8*)((const char*)k_s + byte);
    acc[nt] = __builtin_amdgcn_mfma_f32_16x16x32_f16(
        afrag, bfrag, (f32x4){0.f, 0.f, 0.f, 0.f}, 0, 0, 0);
  }

  // ---- mask + scale: lane holds [nt][reg] = logits[q=(lk&1)*4+reg][rt] -----
  const float scale = 0.17677669529663687f;  // 32^-0.5
  const int qg = lk & 1;                     // row-group (0: q0-3, 1: q4-7)
  float lv[4][4];
#pragma unroll
  for (int nt = 0; nt < 4; ++nt) {
    const int rt = nt * 16 + lr;
    const int tc = rt & 7;
#pragma unroll
    for (int reg = 0; reg < 4; ++reg) {
      const int qq = qg * 4 + reg;
      const int dl = (qq & 2) ? dlt : 0;
      const bool valid = (rt < 56) && ((unsigned)(tc - dl) < 7u);
      lv[nt][reg] = valid ? acc[nt][reg] * scale : -1e30f;
    }
  }

  // ---- softmax per (q): reduce over 16 tap-lanes x 4 tiles ------------------
  float mx[4], sm[4];
#pragma unroll
  for (int reg = 0; reg < 4; ++reg) {
    float m = fmaxf(fmaxf(lv[0][reg], lv[1][reg]), fmaxf(lv[2][reg], lv[3][reg]));
    m = fmaxf(m, __shfl_xor(m, 1));
    m = fmaxf(m, __shfl_xor(m, 2));
    m = fmaxf(m, __shfl_xor(m, 4));
    m = fmaxf(m, __shfl_xor(m, 8));
    mx[reg] = m;
  }
#pragma unroll
  for (int reg = 0; reg < 4; ++reg) {
    float s = 0.f;
#pragma unroll
    for (int nt = 0; nt < 4; ++nt) {
      lv[nt][reg] = __expf(lv[nt][reg] - mx[reg]);
      s += lv[nt][reg];
    }
    s += __shfl_xor(s, 1);
    s += __shfl_xor(s, 2);
    s += __shfl_xor(s, 4);
    s += __shfl_xor(s, 8);
    sm[reg] = 1.f / (8.f * s);
  }

  // ---- p write (lanes < 32 hold real rows 0-7): f16 [h][rt][q] -------------
  if (l < 32) {
#pragma unroll
    for (int nt = 0; nt < 4; ++nt) {
      const int rt = nt * 16 + lr;
      uint2 pk;
      pk.x = pkrtz(lv[nt][0] * sm[0], lv[nt][1] * sm[1]);
      pk.y = pkrtz(lv[nt][2] * sm[2], lv[nt][3] * sm[3]);
      *(uint2*)((char*)p_s + w * 1024 + rt * 16 + qg * 8) = pk;
    }
  }
  __syncthreads();                         // barrier 2: p complete

  // ---- head-sum -> pm_s[q][rt] (first 256 threads: q-pair x 64 rt) ---------
  if (u < 256) {
    const int qp = u & 3;                  // q pair (2qp, 2qp+1)
    const int rt = u >> 2;
    float s0 = 0.f, s1 = 0.f;
#pragma unroll
    for (int h = 0; h < 8; ++h) {
      const uint32_t d = *(const uint32_t*)((const char*)p_s + h * 1024 +
                                            rt * 16 + qp * 4);
      const float2 f = __half22float2(*(const __half2*)&d);
      s0 += f.x;
      s1 += f.y;
    }
    pm_s[2 * qp + 0][rt] = s0;
    pm_s[2 * qp + 1][rt] = s1;
  }
  __syncthreads();                         // barrier 3: pm ready

  // ---- PV: wave = query w, lane = 2-channel slot; pm=0 at invalid taps -----
  float ax = 0.f, ay = 0.f;
#pragma unroll
  for (int t0 = 0; t0 < 56; t0 += 4) {
    const float4 pm4 = *(const float4*)&pm_s[w][t0];
    const uint32_t v0 = v_s[(t0 + 0) * 64 + l];
    const uint32_t v1 = v_s[(t0 + 1) * 64 + l];
    const uint32_t v2 = v_s[(t0 + 2) * 64 + l];
    const uint32_t v3 = v_s[(t0 + 3) * 64 + l];
    const float2 f0 = __half22float2(*(const __half2*)&v0);
    const float2 f1 = __half22float2(*(const __half2*)&v1);
    const float2 f2 = __half22float2(*(const __half2*)&v2);
    const float2 f3 = __half22float2(*(const __half2*)&v3);
    ax += pm4.x * f0.x + pm4.y * f1.x + pm4.z * f2.x + pm4.w * f3.x;
    ay += pm4.x * f0.y + pm4.y * f1.y + pm4.z * f2.y + pm4.w * f3.y;
  }
  const int qx = 2 * a + (w >> 2);
  const int qy = 4 * b + (w & 3);
  const int posq = qx * WQ + qy;
  out[(size_t)(2 * l + 0) * NPOS_Q + posq] = ax;
  out[(size_t)(2 * l + 1) * NPOS_Q + posq] = ay;
}

// ---------------------------------------------------------------------------
extern "C" void kernel_launch(void* const* d_in, const int* in_sizes, int n_in,
                              void* d_out, int out_size, void* d_ws, size_t ws_size,
                              hipStream_t stream) {
  const float* q   = (const float*)d_in[0];
  const float* k   = (const float*)d_in[1];
  const float* v   = (const float*)d_in[2];
  const float* w_q = (const float*)d_in[3];
  const float* b_q = (const float*)d_in[4];
  const float* w_k = (const float*)d_in[5];
  const float* b_k = (const float*)d_in[6];
  float* out = (float*)d_out;

  __half* xtq = (__half*)d_ws;                     // [9216][256] f16 (x^T)
  __half* xtk = xtq + (size_t)NPOS_Q * C_IN;       // [2304][256]
  __half* vt  = xtk + (size_t)NPOS_K * C_IN;       // [2304][128]
  __half* wqh = vt + (size_t)NPOS_K * C_V;         // [256][256] f16
  __half* wkh = wqh + 65536;                       // [256][256]
  __half* qt  = wkh + 65536;                       // [9216][256] f16
  __half* kt  = qt + (size_t)NPOS_Q * C_IN;        // [2304][256]

  prep<<<412, 256, 0, stream>>>(q, k, v, w_q, w_k,
                                (uint32_t*)xtq, (uint32_t*)xtk, (uint32_t*)vt,
                                (uint32_t*)wqh, (uint32_t*)wkh);
  proj_mfma<<<dim3(180, 4), 256, 0, stream>>>(xtq, xtk, wqh, wkh, b_q, b_k, qt, kt);
  natten_attn<<<dim3(HQ / 2, WQ / 4), 512, 0, stream>>>(qt, kt, vt, out);
}